// Round 1
// baseline (2471.998 us; speedup 1.0000x reference)
//
#include <hip/hip_runtime.h>
#include <hip/hip_bf16.h>
#include <math.h>

// CapsNet fp32 baseline.
// ws layout (floats): c1[26,214,400] | c2[2,359,296] (squash in-place -> u) | vbuf[40,960]
// total ws requirement ~114.5 MB.

// ---------------- conv1: x[256,1,28,28] -> c1[256,256,20,20] (+bias, ReLU) ----------------
__global__ __launch_bounds__(256) void conv1_kernel(
    const float* __restrict__ x, const float* __restrict__ w,
    const float* __restrict__ bias, float* __restrict__ out)
{
    const int b = blockIdx.y;        // 256
    const int cg = blockIdx.x;       // 16 groups of 16 channels
    const int t = threadIdx.x;

    __shared__ float xs[784];
    __shared__ float wt[81 * 16];    // [k][cc] transposed
    __shared__ float bs[16];

    for (int i = t; i < 784; i += 256) xs[i] = x[b * 784 + i];
    for (int i = t; i < 1296; i += 256) {
        int k = i >> 4, cc = i & 15;
        wt[i] = w[(cg * 16 + cc) * 81 + k];
    }
    if (t < 16) bs[t] = bias[cg * 16 + t];
    __syncthreads();

    if (t < 200) {
        const int pos = t * 2;
        const int oy = pos / 20, ox = pos % 20;
        float4 A0[4], A1[4];
        #pragma unroll
        for (int g = 0; g < 4; ++g) { A0[g] = make_float4(0,0,0,0); A1[g] = make_float4(0,0,0,0); }

        for (int ky = 0; ky < 9; ++ky) {
            const float* xr = &xs[(oy + ky) * 28 + ox];
            #pragma unroll
            for (int kx = 0; kx < 9; ++kx) {
                float x0 = xr[kx], x1 = xr[kx + 1];
                const float4* wp = (const float4*)&wt[(ky * 9 + kx) << 4];
                #pragma unroll
                for (int g = 0; g < 4; ++g) {
                    float4 wv = wp[g];
                    A0[g].x = fmaf(x0, wv.x, A0[g].x); A0[g].y = fmaf(x0, wv.y, A0[g].y);
                    A0[g].z = fmaf(x0, wv.z, A0[g].z); A0[g].w = fmaf(x0, wv.w, A0[g].w);
                    A1[g].x = fmaf(x1, wv.x, A1[g].x); A1[g].y = fmaf(x1, wv.y, A1[g].y);
                    A1[g].z = fmaf(x1, wv.z, A1[g].z); A1[g].w = fmaf(x1, wv.w, A1[g].w);
                }
            }
        }
        #pragma unroll
        for (int g = 0; g < 4; ++g) {
            float v0[4] = {A0[g].x, A0[g].y, A0[g].z, A0[g].w};
            float v1[4] = {A1[g].x, A1[g].y, A1[g].z, A1[g].w};
            #pragma unroll
            for (int q = 0; q < 4; ++q) {
                int cc = g * 4 + q;
                size_t base = (size_t)(b * 256 + cg * 16 + cc) * 400 + pos;
                out[base]     = fmaxf(v0[q] + bs[cc], 0.f);
                out[base + 1] = fmaxf(v1[q] + bs[cc], 0.f);
            }
        }
    }
}

// ---------------- conv2: c1 -> flat [256][9216] (c*36 + oy*6 + ox), +bias, ReLU ----------------
#define C2_CHUNK 2
__global__ __launch_bounds__(384) void conv2_kernel(
    const float* __restrict__ in,    // [256,256,400]
    const float* __restrict__ w,     // [256,256,81]
    const float* __restrict__ bias,  // [256]
    float* __restrict__ out)         // [256,9216]
{
    const int bg = blockIdx.y;       // 64 groups of 4 batches
    const int ct = blockIdx.x;       // 4 tiles of 64 c_out
    const int t = threadIdx.x;       // 384

    __shared__ float wl[C2_CHUNK][81][64];        // [ci][k][c_out]
    __shared__ float il[C2_CHUNK][4][20][24];     // parity-split: [0..9]=even cols, [12..21]=odd

    const int cg = t & 15;           // c_out group of 4
    const int slot = t >> 4;         // 0..23
    const int bb = slot / 6;
    const int oy = slot % 6;

    float4 acc[6];
    #pragma unroll
    for (int i = 0; i < 6; ++i) acc[i] = make_float4(0,0,0,0);

    for (int cc0 = 0; cc0 < 256; cc0 += C2_CHUNK) {
        for (int idx = t; idx < C2_CHUNK * 5184; idx += 384) {
            int ci = idx / 5184;
            int r = idx - ci * 5184;
            int kk = r >> 6;
            int co = r & 63;
            wl[ci][kk][co] = w[(size_t)(ct * 64 + co) * 20736 + (cc0 + ci) * 81 + kk];
        }
        for (int idx = t; idx < C2_CHUNK * 1600; idx += 384) {
            int ci = idx / 1600;
            int r = idx - ci * 1600;
            int bb2 = r / 400;
            int p = r - bb2 * 400;
            int y = p / 20;
            int xx = p - y * 20;
            il[ci][bb2][y][(xx & 1) * 12 + (xx >> 1)] =
                in[(size_t)((bg * 4 + bb2) * 256 + cc0 + ci) * 400 + p];
        }
        __syncthreads();

        #pragma unroll
        for (int ci = 0; ci < C2_CHUNK; ++ci) {
            for (int ky = 0; ky < 9; ++ky) {
                const int y = oy * 2 + ky;
                const float4* rowp = (const float4*)&il[ci][bb][y][0];
                float a[24];
                #pragma unroll
                for (int q = 0; q < 6; ++q) *(((float4*)a) + q) = rowp[q];
                #pragma unroll
                for (int kx = 0; kx < 9; ++kx) {
                    const int k = ky * 9 + kx;
                    float4 wv = *(const float4*)&wl[ci][k][cg * 4];
                    const int base = (kx & 1) ? (12 + (kx >> 1)) : (kx >> 1);
                    #pragma unroll
                    for (int ox = 0; ox < 6; ++ox) {
                        float av = a[base + ox];
                        acc[ox].x = fmaf(av, wv.x, acc[ox].x);
                        acc[ox].y = fmaf(av, wv.y, acc[ox].y);
                        acc[ox].z = fmaf(av, wv.z, acc[ox].z);
                        acc[ox].w = fmaf(av, wv.w, acc[ox].w);
                    }
                }
            }
        }
        __syncthreads();
    }

    const int b = bg * 4 + bb;
    const int c0 = ct * 64 + cg * 4;
    float4 bv = *(const float4*)&bias[c0];
    #pragma unroll
    for (int ox = 0; ox < 6; ++ox) {
        int s = oy * 6 + ox;
        size_t ob = (size_t)b * 9216 + s;
        out[ob + (size_t)(c0 + 0) * 36] = fmaxf(acc[ox].x + bv.x, 0.f);
        out[ob + (size_t)(c0 + 1) * 36] = fmaxf(acc[ox].y + bv.y, 0.f);
        out[ob + (size_t)(c0 + 2) * 36] = fmaxf(acc[ox].z + bv.z, 0.f);
        out[ob + (size_t)(c0 + 3) * 36] = fmaxf(acc[ox].w + bv.w, 0.f);
    }
}

// ---------------- squash in-place over groups of 8 ----------------
__global__ __launch_bounds__(256) void squash_kernel(float* __restrict__ h)
{
    const int cap = blockIdx.x * 256 + threadIdx.x;   // 294912 capsules
    float4* p = (float4*)(h + (size_t)cap * 8);
    float4 v0 = p[0], v1 = p[1];
    float sq = v0.x*v0.x + v0.y*v0.y + v0.z*v0.z + v0.w*v0.w
             + v1.x*v1.x + v1.y*v1.y + v1.z*v1.z + v1.w*v1.w;
    float scale = (sq / (1.f + sq)) / sqrtf(sq + 1e-8f);
    v0.x *= scale; v0.y *= scale; v0.z *= scale; v0.w *= scale;
    v1.x *= scale; v1.y *= scale; v1.z *= scale; v1.w *= scale;
    p[0] = v0; p[1] = v1;
}

// ---------------- fused u_hat + dynamic routing per (b,c) ----------------
__global__ __launch_bounds__(256) void routing_kernel(
    const float* __restrict__ u,     // [256,1152,8]
    const float* __restrict__ W,     // [10,1152,8,16]
    float* __restrict__ cp_out,      // [256,10] -> d_out
    float* __restrict__ vbuf)        // [256,10,16]
{
    const int b = blockIdx.x;
    const int c = blockIdx.y;
    const int t = threadIdx.x;
    const int lane = t & 63, wid = t >> 6;

    __shared__ float uh[1152 * 16];  // 73.7 KB
    __shared__ float us[9216];       // 36.9 KB
    __shared__ float bl[1152];
    __shared__ float cl[1152];
    __shared__ float red[256];
    __shared__ float rtmp[8];
    __shared__ float vv[16];

    {
        const float4* ug = (const float4*)(u + (size_t)b * 9216);
        float4* us4 = (float4*)us;
        for (int i = t; i < 2304; i += 256) us4[i] = ug[i];
    }
    for (int i = t; i < 1152; i += 256) bl[i] = 0.f;
    __syncthreads();

    // u_hat[n][f] = sum_d u[b][n][d] * W[c][n][d][f]
    {
        const int fg = t & 3, ng = t >> 2;
        const float* Wc = W + (size_t)c * 147456;
        for (int j = 0; j < 18; ++j) {
            int n = ng + (j << 6);
            const float* wn = Wc + n * 128 + fg * 4;
            const float* un = us + n * 8;
            float ax = 0.f, ay = 0.f, az = 0.f, aw = 0.f;
            #pragma unroll
            for (int d = 0; d < 8; ++d) {
                float4 w4 = *(const float4*)(wn + (d << 4));
                float ud = un[d];
                ax = fmaf(ud, w4.x, ax);
                ay = fmaf(ud, w4.y, ay);
                az = fmaf(ud, w4.z, az);
                aw = fmaf(ud, w4.w, aw);
            }
            *(float4*)&uh[(n << 4) + (fg << 2)] = make_float4(ax, ay, az, aw);
        }
    }
    __syncthreads();

    for (int it = 0; it < 3; ++it) {
        // softmax over n: max
        float m = -1e30f;
        for (int i = t; i < 1152; i += 256) m = fmaxf(m, bl[i]);
        #pragma unroll
        for (int o = 32; o > 0; o >>= 1) m = fmaxf(m, __shfl_xor(m, o));
        if (lane == 0) rtmp[wid] = m;
        __syncthreads();
        m = fmaxf(fmaxf(rtmp[0], rtmp[1]), fmaxf(rtmp[2], rtmp[3]));
        // exp + sum
        float sum = 0.f;
        for (int i = t; i < 1152; i += 256) {
            float e = expf(bl[i] - m);
            cl[i] = e;
            sum += e;
        }
        #pragma unroll
        for (int o = 32; o > 0; o >>= 1) sum += __shfl_xor(sum, o);
        if (lane == 0) rtmp[4 + wid] = sum;
        __syncthreads();
        float inv = 1.f / (rtmp[4] + rtmp[5] + rtmp[6] + rtmp[7]);

        // s[f] = inv * sum_n cl[n]*uh[n][f]
        const int f = t & 15, g = t >> 4;
        float sacc = 0.f;
        for (int n = g; n < 1152; n += 16)
            sacc = fmaf(cl[n], uh[(n << 4) + f], sacc);
        red[(g << 4) + f] = sacc;
        __syncthreads();
        if (t < 16) {
            float sv = 0.f;
            #pragma unroll
            for (int gg = 0; gg < 16; ++gg) sv += red[(gg << 4) + t];
            sv *= inv;
            float sq = sv * sv;
            #pragma unroll
            for (int o = 8; o > 0; o >>= 1) sq += __shfl_xor(sq, o);
            float scale = (sq / (1.f + sq)) / sqrtf(sq + 1e-8f);
            vv[t] = sv * scale;
        }
        __syncthreads();
        if (it < 2) {
            for (int n = t; n < 1152; n += 256) {
                const float4* up = (const float4*)&uh[n << 4];
                float4 q0 = up[0], q1 = up[1], q2 = up[2], q3 = up[3];
                float dot =
                    q0.x*vv[0]  + q0.y*vv[1]  + q0.z*vv[2]  + q0.w*vv[3] +
                    q1.x*vv[4]  + q1.y*vv[5]  + q1.z*vv[6]  + q1.w*vv[7] +
                    q2.x*vv[8]  + q2.y*vv[9]  + q2.z*vv[10] + q2.w*vv[11] +
                    q3.x*vv[12] + q3.y*vv[13] + q3.z*vv[14] + q3.w*vv[15];
                bl[n] += dot;
            }
            __syncthreads();
        }
    }

    if (t < 16) {
        float v_ = vv[t];
        float s2 = v_ * v_;
        #pragma unroll
        for (int o = 8; o > 0; o >>= 1) s2 += __shfl_xor(s2, o);
        if (t == 0) cp_out[b * 10 + c] = sqrtf(s2 + 1e-8f);
        vbuf[((b * 10 + c) << 4) + t] = v_;
    }
}

// ---------------- decoder: argmax-mask -> 160->512->1024->784 ----------------
__global__ __launch_bounds__(256) void decoder_kernel(
    const float* __restrict__ cp, const float* __restrict__ vbuf,
    const float* __restrict__ W1, const float* __restrict__ B1,
    const float* __restrict__ W2, const float* __restrict__ B2,
    const float* __restrict__ W3, const float* __restrict__ B3,
    float* __restrict__ out)
{
    const int b = blockIdx.x, t = threadIdx.x;
    __shared__ float r16[16];
    __shared__ float h1[512];
    __shared__ float h2[1024];

    float best = cp[b * 10];
    int idx = 0;
    #pragma unroll
    for (int cc = 1; cc < 10; ++cc) {
        float p = cp[b * 10 + cc];
        if (p > best) { best = p; idx = cc; }
    }
    if (t < 16) r16[t] = vbuf[(b * 10 + idx) * 16 + t];
    __syncthreads();

    {   // layer 1: only 16 rows of W1 are live (one-hot mask)
        float a0 = B1[t], a1 = B1[t + 256];
        const float* w = W1 + (size_t)idx * 16 * 512 + t;
        #pragma unroll
        for (int k = 0; k < 16; ++k) {
            float rv = r16[k];
            a0 = fmaf(rv, w[k * 512], a0);
            a1 = fmaf(rv, w[k * 512 + 256], a1);
        }
        h1[t] = fmaxf(a0, 0.f);
        h1[t + 256] = fmaxf(a1, 0.f);
    }
    __syncthreads();

    {   // layer 2
        float a0 = B2[t], a1 = B2[t + 256], a2 = B2[t + 512], a3 = B2[t + 768];
        #pragma unroll 4
        for (int k = 0; k < 512; ++k) {
            float hv = h1[k];
            const float* w = W2 + (size_t)k * 1024 + t;
            a0 = fmaf(hv, w[0], a0);
            a1 = fmaf(hv, w[256], a1);
            a2 = fmaf(hv, w[512], a2);
            a3 = fmaf(hv, w[768], a3);
        }
        h2[t] = fmaxf(a0, 0.f);
        h2[t + 256] = fmaxf(a1, 0.f);
        h2[t + 512] = fmaxf(a2, 0.f);
        h2[t + 768] = fmaxf(a3, 0.f);
    }
    __syncthreads();

    {   // layer 3 (784 outputs)
        float a0 = B3[t], a1 = B3[t + 256], a2 = B3[t + 512];
        #pragma unroll 4
        for (int k = 0; k < 1024; ++k) {
            float hv = h2[k];
            const float* w = W3 + (size_t)k * 784 + t;
            a0 = fmaf(hv, w[0], a0);
            a1 = fmaf(hv, w[256], a1);
            a2 = fmaf(hv, w[512], a2);
        }
        size_t ob = (size_t)b * 784;
        out[ob + t]       = 1.f / (1.f + expf(-a0));
        out[ob + t + 256] = 1.f / (1.f + expf(-a1));
        out[ob + t + 512] = 1.f / (1.f + expf(-a2));
        if (t < 16) {
            float a3 = B3[t + 768];
            for (int k = 0; k < 1024; ++k)
                a3 = fmaf(h2[k], W3[(size_t)k * 784 + t + 768], a3);
            out[ob + t + 768] = 1.f / (1.f + expf(-a3));
        }
    }
}

extern "C" void kernel_launch(void* const* d_in, const int* in_sizes, int n_in,
                              void* d_out, int out_size, void* d_ws, size_t ws_size,
                              hipStream_t stream) {
    const float* x   = (const float*)d_in[0];
    const float* w1  = (const float*)d_in[1];
    const float* b1  = (const float*)d_in[2];
    const float* w2  = (const float*)d_in[3];
    const float* b2  = (const float*)d_in[4];
    const float* W   = (const float*)d_in[5];
    const float* dw1 = (const float*)d_in[6];
    const float* db1 = (const float*)d_in[7];
    const float* dw2 = (const float*)d_in[8];
    const float* db2 = (const float*)d_in[9];
    const float* dw3 = (const float*)d_in[10];
    const float* db3 = (const float*)d_in[11];

    float* ws   = (float*)d_ws;
    float* c1   = ws;                       // 26,214,400
    float* c2   = c1 + 26214400;            // 2,359,296 (squash in-place -> u)
    float* vbuf = c2 + 2359296;             // 40,960
    float* outp = (float*)d_out;            // [2560 class_probs][200704 recons]

    conv1_kernel<<<dim3(16, 256), 256, 0, stream>>>(x, w1, b1, c1);
    conv2_kernel<<<dim3(4, 64), 384, 0, stream>>>(c1, w2, b2, c2);
    squash_kernel<<<1152, 256, 0, stream>>>(c2);
    routing_kernel<<<dim3(256, 10), 256, 0, stream>>>(c2, W, outp, vbuf);
    decoder_kernel<<<256, 256, 0, stream>>>(outp, vbuf, dw1, db1, dw2, db2, dw3, db3, outp + 2560);
}

// Round 2
// 876.625 us; speedup vs baseline: 2.8199x; 2.8199x over previous
//
#include <hip/hip_runtime.h>
#include <hip/hip_bf16.h>
#include <math.h>

typedef __bf16 bf16;
typedef bf16 bf16x8 __attribute__((ext_vector_type(8)));
typedef float f32x16 __attribute__((ext_vector_type(16)));

// ws layout (f32 slot offsets), fast path:
//   Ah  bf16[26214400] @ 0           (13107200 f32 slots)
//   Al  bf16[26214400] @ 13107200
//   Wh  bf16[5308416]  @ 26214400    (2654208 slots)
//   Wl  bf16[5308416]  @ 28868608
//   partial f32 ks*2359296 @ 31522816
//   vbuf f32 40960 @ 31522816 + ks*2359296
//   u   f32[2359296]  @ 0 (overlays Ah after conv2 is done)

// ---------------- conv1: x[256,1,28,28] -> bf16 hi/lo channels-last [b][400][256]
// mode 0: bf16 pair channels-last; mode 1: f32 old layout [b][c][400] (fallback)
__global__ __launch_bounds__(256) void conv1_kernel(
    const float* __restrict__ x, const float* __restrict__ w,
    const float* __restrict__ bias, bf16* __restrict__ outh,
    bf16* __restrict__ outl, float* __restrict__ outf, int mode)
{
    const int b = blockIdx.y;
    const int cg = blockIdx.x;       // 16 groups of 16 channels
    const int t = threadIdx.x;

    __shared__ float xs[784];
    __shared__ float wt[81 * 16];
    __shared__ float bs[16];

    for (int i = t; i < 784; i += 256) xs[i] = x[b * 784 + i];
    for (int i = t; i < 1296; i += 256) {
        int k = i >> 4, cc = i & 15;
        wt[i] = w[(cg * 16 + cc) * 81 + k];
    }
    if (t < 16) bs[t] = bias[cg * 16 + t];
    __syncthreads();

    if (t >= 200) return;
    const int pos = t * 2;
    const int oy = pos / 20, ox = pos % 20;
    float4 A0[4], A1[4];
    #pragma unroll
    for (int g = 0; g < 4; ++g) { A0[g] = make_float4(0,0,0,0); A1[g] = make_float4(0,0,0,0); }

    for (int ky = 0; ky < 9; ++ky) {
        const float* xr = &xs[(oy + ky) * 28 + ox];
        #pragma unroll
        for (int kx = 0; kx < 9; ++kx) {
            float x0 = xr[kx], x1 = xr[kx + 1];
            const float4* wp = (const float4*)&wt[(ky * 9 + kx) << 4];
            #pragma unroll
            for (int g = 0; g < 4; ++g) {
                float4 wv = wp[g];
                A0[g].x = fmaf(x0, wv.x, A0[g].x); A0[g].y = fmaf(x0, wv.y, A0[g].y);
                A0[g].z = fmaf(x0, wv.z, A0[g].z); A0[g].w = fmaf(x0, wv.w, A0[g].w);
                A1[g].x = fmaf(x1, wv.x, A1[g].x); A1[g].y = fmaf(x1, wv.y, A1[g].y);
                A1[g].z = fmaf(x1, wv.z, A1[g].z); A1[g].w = fmaf(x1, wv.w, A1[g].w);
            }
        }
    }

    float va[16], vb[16];
    #pragma unroll
    for (int g = 0; g < 4; ++g) {
        va[g*4+0] = fmaxf(A0[g].x + bs[g*4+0], 0.f);
        va[g*4+1] = fmaxf(A0[g].y + bs[g*4+1], 0.f);
        va[g*4+2] = fmaxf(A0[g].z + bs[g*4+2], 0.f);
        va[g*4+3] = fmaxf(A0[g].w + bs[g*4+3], 0.f);
        vb[g*4+0] = fmaxf(A1[g].x + bs[g*4+0], 0.f);
        vb[g*4+1] = fmaxf(A1[g].y + bs[g*4+1], 0.f);
        vb[g*4+2] = fmaxf(A1[g].z + bs[g*4+2], 0.f);
        vb[g*4+3] = fmaxf(A1[g].w + bs[g*4+3], 0.f);
    }

    if (mode == 0) {
        size_t base0 = ((size_t)b * 400 + pos) * 256 + cg * 16;
        bf16x8 H, L;
        #pragma unroll
        for (int q = 0; q < 8; ++q) { bf16 hh = (bf16)va[q]; H[q] = hh; L[q] = (bf16)(va[q] - (float)hh); }
        *(bf16x8*)(outh + base0) = H; *(bf16x8*)(outl + base0) = L;
        #pragma unroll
        for (int q = 0; q < 8; ++q) { bf16 hh = (bf16)va[8+q]; H[q] = hh; L[q] = (bf16)(va[8+q] - (float)hh); }
        *(bf16x8*)(outh + base0 + 8) = H; *(bf16x8*)(outl + base0 + 8) = L;
        size_t base1 = base0 + 256;
        #pragma unroll
        for (int q = 0; q < 8; ++q) { bf16 hh = (bf16)vb[q]; H[q] = hh; L[q] = (bf16)(vb[q] - (float)hh); }
        *(bf16x8*)(outh + base1) = H; *(bf16x8*)(outl + base1) = L;
        #pragma unroll
        for (int q = 0; q < 8; ++q) { bf16 hh = (bf16)vb[8+q]; H[q] = hh; L[q] = (bf16)(vb[8+q] - (float)hh); }
        *(bf16x8*)(outh + base1 + 8) = H; *(bf16x8*)(outl + base1 + 8) = L;
    } else {
        #pragma unroll
        for (int q = 0; q < 16; ++q) {
            size_t base = (size_t)(b * 256 + cg * 16 + q) * 400 + pos;
            outf[base] = va[q]; outf[base + 1] = vb[q];
        }
    }
}

// ---------------- weight prep: w[co][ci][81] f32 -> Wh/Wl bf16 [tap][co][ci] ----------------
__global__ __launch_bounds__(256) void wprep_kernel(
    const float* __restrict__ w, bf16* __restrict__ Wh, bf16* __restrict__ Wl)
{
    const int co = blockIdx.x, t = threadIdx.x;
    __shared__ float wl[20736];
    for (int i = t; i < 20736; i += 256) wl[i] = w[(size_t)co * 20736 + i];
    __syncthreads();
    for (int tap = 0; tap < 81; ++tap) {
        float f = wl[t * 81 + tap];
        bf16 h = (bf16)f;
        size_t o = ((size_t)tap * 256 + co) * 256 + t;
        Wh[o] = h;
        Wl[o] = (bf16)(f - (float)h);
    }
}

// ---------------- conv2 via split-bf16 MFMA, split-K, partial f32 out ----------------
// A: [b][400pos][256ci] bf16 (hi,lo). B: [81tap][256co][256ci] bf16 (hi,lo).
// partial[kslice][m=b*36+s][co] f32. block: 128m x 128co, 4 waves (2x2), wave 64x64.
__global__ __launch_bounds__(256, 2) void conv2_mfma(
    const bf16* __restrict__ Ah, const bf16* __restrict__ Al,
    const bf16* __restrict__ Bh, const bf16* __restrict__ Bl,
    float* __restrict__ partial, int nslice, int spk)
{
    const int ncombo = 2 * nslice;
    const int combo = blockIdx.x % ncombo;   // round-robins across XCDs
    const int mblk  = blockIdx.x / ncombo;
    const int coblk = combo & 1;
    const int kslice = combo >> 1;

    const int t = threadIdx.x;
    const int lane = t & 63, wv = t >> 6;
    const int wm = wv >> 1, wn = wv & 1;

    // padded rows: 40 bf16 = 80B (16B-aligned, bank-spread)
    __shared__ bf16 sAh[128 * 40], sAl[128 * 40], sBh[128 * 40], sBl[128 * 40];

    // staging: each thread loads 2 A-rows and 2 B-rows, 16B (slot) each, for hi and lo
    const int slot = t & 3;
    const int r0 = t >> 2;                  // 0..63
    const int m0 = mblk * 128 + r0;
    const int m1 = m0 + 64;
    const int b0 = m0 / 36, s0 = m0 % 36;
    const int b1 = m1 / 36, s1 = m1 % 36;
    const int pa0 = b0 * 102400 + ((s0 / 6) * 40 + (s0 % 6) * 2) * 256 + slot * 8;
    const int pa1 = b1 * 102400 + ((s1 / 6) * 40 + (s1 % 6) * 2) * 256 + slot * 8;
    const int pb0 = (coblk * 128 + r0) * 256 + slot * 8;
    const int pb1 = pb0 + 64 * 256;

    // LDS write dests (elements)
    const int d0 = r0 * 40 + slot * 8;
    const int d1 = d0 + 64 * 40;

    // frag read bases (elements): row*40 + (lane>>5)*8
    const int la = (wm * 64 + (lane & 31)) * 40 + (lane >> 5) * 8;
    const int lb = (wn * 64 + (lane & 31)) * 40 + (lane >> 5) * 8;

    f32x16 acc00 = {}, acc01 = {}, acc10 = {}, acc11 = {};

    bf16x8 rAh0, rAh1, rAl0, rAl1, rBh0, rBh1, rBl0, rBl1;

    const int g0 = kslice * spk;
    auto load_step = [&](int gstep) {
        const int tap = gstep >> 3;
        const int cic = (gstep & 7) << 5;
        const int ky = tap / 9, kx = tap - ky * 9;
        const int aoff = (ky * 20 + kx) * 256 + cic;
        const int boff = tap * 65536 + cic;
        rAh0 = *(const bf16x8*)(Ah + pa0 + aoff);
        rAh1 = *(const bf16x8*)(Ah + pa1 + aoff);
        rAl0 = *(const bf16x8*)(Al + pa0 + aoff);
        rAl1 = *(const bf16x8*)(Al + pa1 + aoff);
        rBh0 = *(const bf16x8*)(Bh + pb0 + boff);
        rBh1 = *(const bf16x8*)(Bh + pb1 + boff);
        rBl0 = *(const bf16x8*)(Bl + pb0 + boff);
        rBl1 = *(const bf16x8*)(Bl + pb1 + boff);
    };

    load_step(g0);

    for (int s = 0; s < spk; ++s) {
        // write staged regs to LDS
        *(bf16x8*)&sAh[d0] = rAh0; *(bf16x8*)&sAh[d1] = rAh1;
        *(bf16x8*)&sAl[d0] = rAl0; *(bf16x8*)&sAl[d1] = rAl1;
        *(bf16x8*)&sBh[d0] = rBh0; *(bf16x8*)&sBh[d1] = rBh1;
        *(bf16x8*)&sBl[d0] = rBl0; *(bf16x8*)&sBl[d1] = rBl1;
        __syncthreads();

        if (s + 1 < spk) load_step(g0 + s + 1);   // prefetch overlaps compute

        #pragma unroll
        for (int h = 0; h < 2; ++h) {
            const int o = h * 16;
            bf16x8 a0h = *(const bf16x8*)&sAh[la + o];
            bf16x8 a0l = *(const bf16x8*)&sAl[la + o];
            bf16x8 a1h = *(const bf16x8*)&sAh[la + 1280 + o];
            bf16x8 a1l = *(const bf16x8*)&sAl[la + 1280 + o];
            bf16x8 b0h = *(const bf16x8*)&sBh[lb + o];
            bf16x8 b0l = *(const bf16x8*)&sBl[lb + o];
            bf16x8 b1h = *(const bf16x8*)&sBh[lb + 1280 + o];
            bf16x8 b1l = *(const bf16x8*)&sBl[lb + 1280 + o];
            acc00 = __builtin_amdgcn_mfma_f32_32x32x16_bf16(a0h, b0h, acc00, 0, 0, 0);
            acc00 = __builtin_amdgcn_mfma_f32_32x32x16_bf16(a0h, b0l, acc00, 0, 0, 0);
            acc00 = __builtin_amdgcn_mfma_f32_32x32x16_bf16(a0l, b0h, acc00, 0, 0, 0);
            acc01 = __builtin_amdgcn_mfma_f32_32x32x16_bf16(a0h, b1h, acc01, 0, 0, 0);
            acc01 = __builtin_amdgcn_mfma_f32_32x32x16_bf16(a0h, b1l, acc01, 0, 0, 0);
            acc01 = __builtin_amdgcn_mfma_f32_32x32x16_bf16(a0l, b1h, acc01, 0, 0, 0);
            acc10 = __builtin_amdgcn_mfma_f32_32x32x16_bf16(a1h, b0h, acc10, 0, 0, 0);
            acc10 = __builtin_amdgcn_mfma_f32_32x32x16_bf16(a1h, b0l, acc10, 0, 0, 0);
            acc10 = __builtin_amdgcn_mfma_f32_32x32x16_bf16(a1l, b0h, acc10, 0, 0, 0);
            acc11 = __builtin_amdgcn_mfma_f32_32x32x16_bf16(a1h, b1h, acc11, 0, 0, 0);
            acc11 = __builtin_amdgcn_mfma_f32_32x32x16_bf16(a1h, b1l, acc11, 0, 0, 0);
            acc11 = __builtin_amdgcn_mfma_f32_32x32x16_bf16(a1l, b1h, acc11, 0, 0, 0);
        }
        __syncthreads();
    }

    // epilogue: partial[kslice][row][col]
    float* pp = partial + (size_t)kslice * 2359296;
    const int colb = coblk * 128 + wn * 64 + (lane & 31);
    const int rowb = mblk * 128 + wm * 64 + 4 * (lane >> 5);
    #pragma unroll
    for (int a = 0; a < 2; ++a) {
        #pragma unroll
        for (int nb = 0; nb < 2; ++nb) {
            const f32x16 v = (a == 0) ? (nb == 0 ? acc00 : acc01) : (nb == 0 ? acc10 : acc11);
            const int col = colb + nb * 32;
            const int rb = rowb + a * 32;
            #pragma unroll
            for (int r = 0; r < 16; ++r) {
                int row = rb + (r & 3) + 8 * (r >> 2);
                pp[(size_t)row * 256 + col] = v[r];
            }
        }
    }
}

// ---------------- reduce split-K + bias + relu + squash -> u[b][9216] ----------------
__global__ __launch_bounds__(256) void reduce_kernel(
    const float* __restrict__ partial, const float* __restrict__ bias,
    float* __restrict__ u, int ks)
{
    const int b = blockIdx.x, t = threadIdx.x;
    __shared__ float ld[36 * 257];
    for (int s = 0; s < 36; ++s) {
        size_t idx = ((size_t)b * 36 + s) * 256 + t;
        float a = bias[t];
        for (int k = 0; k < ks; ++k) a += partial[(size_t)k * 2359296 + idx];
        ld[s * 257 + t] = fmaxf(a, 0.f);
    }
    __syncthreads();
    for (int n = t; n < 1152; n += 256) {
        const int f0 = n * 8;
        float vals[8]; float sq = 0.f;
        int co = f0 / 36;
        int s = f0 - co * 36;
        #pragma unroll
        for (int d = 0; d < 8; ++d) {
            float v = ld[s * 257 + co];
            vals[d] = v; sq += v * v;
            if (++s == 36) { s = 0; ++co; }
        }
        float scale = (sq / (1.f + sq)) / sqrtf(sq + 1e-8f);
        #pragma unroll
        for (int d = 0; d < 8; ++d) u[(size_t)b * 9216 + f0 + d] = vals[d] * scale;
    }
}

// ---------------- OLD fallback conv2 (fp32) + squash ----------------
#define C2_CHUNK 2
__global__ __launch_bounds__(384) void conv2_kernel(
    const float* __restrict__ in, const float* __restrict__ w,
    const float* __restrict__ bias, float* __restrict__ out)
{
    const int bg = blockIdx.y;
    const int ct = blockIdx.x;
    const int t = threadIdx.x;

    __shared__ float wl[C2_CHUNK][81][64];
    __shared__ float il[C2_CHUNK][4][20][24];

    const int cg = t & 15;
    const int slot = t >> 4;
    const int bb = slot / 6;
    const int oy = slot % 6;

    float4 acc[6];
    #pragma unroll
    for (int i = 0; i < 6; ++i) acc[i] = make_float4(0,0,0,0);

    for (int cc0 = 0; cc0 < 256; cc0 += C2_CHUNK) {
        for (int idx = t; idx < C2_CHUNK * 5184; idx += 384) {
            int ci = idx / 5184;
            int r = idx - ci * 5184;
            int kk = r >> 6;
            int co = r & 63;
            wl[ci][kk][co] = w[(size_t)(ct * 64 + co) * 20736 + (cc0 + ci) * 81 + kk];
        }
        for (int idx = t; idx < C2_CHUNK * 1600; idx += 384) {
            int ci = idx / 1600;
            int r = idx - ci * 1600;
            int bb2 = r / 400;
            int p = r - bb2 * 400;
            int y = p / 20;
            int xx = p - y * 20;
            il[ci][bb2][y][(xx & 1) * 12 + (xx >> 1)] =
                in[(size_t)((bg * 4 + bb2) * 256 + cc0 + ci) * 400 + p];
        }
        __syncthreads();

        #pragma unroll
        for (int ci = 0; ci < C2_CHUNK; ++ci) {
            for (int ky = 0; ky < 9; ++ky) {
                const int y = oy * 2 + ky;
                const float4* rowp = (const float4*)&il[ci][bb][y][0];
                float a[24];
                #pragma unroll
                for (int q = 0; q < 6; ++q) *(((float4*)a) + q) = rowp[q];
                #pragma unroll
                for (int kx = 0; kx < 9; ++kx) {
                    const int k = ky * 9 + kx;
                    float4 wv = *(const float4*)&wl[ci][k][cg * 4];
                    const int base = (kx & 1) ? (12 + (kx >> 1)) : (kx >> 1);
                    #pragma unroll
                    for (int ox = 0; ox < 6; ++ox) {
                        float av = a[base + ox];
                        acc[ox].x = fmaf(av, wv.x, acc[ox].x);
                        acc[ox].y = fmaf(av, wv.y, acc[ox].y);
                        acc[ox].z = fmaf(av, wv.z, acc[ox].z);
                        acc[ox].w = fmaf(av, wv.w, acc[ox].w);
                    }
                }
            }
        }
        __syncthreads();
    }

    const int b = bg * 4 + bb;
    const int c0 = ct * 64 + cg * 4;
    float4 bv = *(const float4*)&bias[c0];
    #pragma unroll
    for (int ox = 0; ox < 6; ++ox) {
        int sdx = oy * 6 + ox;
        size_t ob = (size_t)b * 9216 + sdx;
        out[ob + (size_t)(c0 + 0) * 36] = fmaxf(acc[ox].x + bv.x, 0.f);
        out[ob + (size_t)(c0 + 1) * 36] = fmaxf(acc[ox].y + bv.y, 0.f);
        out[ob + (size_t)(c0 + 2) * 36] = fmaxf(acc[ox].z + bv.z, 0.f);
        out[ob + (size_t)(c0 + 3) * 36] = fmaxf(acc[ox].w + bv.w, 0.f);
    }
}

__global__ __launch_bounds__(256) void squash_kernel(float* __restrict__ h)
{
    const int cap = blockIdx.x * 256 + threadIdx.x;
    float4* p = (float4*)(h + (size_t)cap * 8);
    float4 v0 = p[0], v1 = p[1];
    float sq = v0.x*v0.x + v0.y*v0.y + v0.z*v0.z + v0.w*v0.w
             + v1.x*v1.x + v1.y*v1.y + v1.z*v1.z + v1.w*v1.w;
    float scale = (sq / (1.f + sq)) / sqrtf(sq + 1e-8f);
    v0.x *= scale; v0.y *= scale; v0.z *= scale; v0.w *= scale;
    v1.x *= scale; v1.y *= scale; v1.z *= scale; v1.w *= scale;
    p[0] = v0; p[1] = v1;
}

// ---------------- fused u_hat + dynamic routing per (b,c) ----------------
__global__ __launch_bounds__(256) void routing_kernel(
    const float* __restrict__ u, const float* __restrict__ W,
    float* __restrict__ cp_out, float* __restrict__ vbuf)
{
    const int b = blockIdx.x;
    const int c = blockIdx.y;
    const int t = threadIdx.x;
    const int lane = t & 63, wid = t >> 6;

    __shared__ float uh[1152 * 16];
    __shared__ float us[9216];
    __shared__ float bl[1152];
    __shared__ float cl[1152];
    __shared__ float red[256];
    __shared__ float rtmp[8];
    __shared__ float vv[16];

    {
        const float4* ug = (const float4*)(u + (size_t)b * 9216);
        float4* us4 = (float4*)us;
        for (int i = t; i < 2304; i += 256) us4[i] = ug[i];
    }
    for (int i = t; i < 1152; i += 256) bl[i] = 0.f;
    __syncthreads();

    {
        const int fg = t & 3, ng = t >> 2;
        const float* Wc = W + (size_t)c * 147456;
        for (int j = 0; j < 18; ++j) {
            int n = ng + (j << 6);
            const float* wn = Wc + n * 128 + fg * 4;
            const float* un = us + n * 8;
            float ax = 0.f, ay = 0.f, az = 0.f, aw = 0.f;
            #pragma unroll
            for (int d = 0; d < 8; ++d) {
                float4 w4 = *(const float4*)(wn + (d << 4));
                float ud = un[d];
                ax = fmaf(ud, w4.x, ax);
                ay = fmaf(ud, w4.y, ay);
                az = fmaf(ud, w4.z, az);
                aw = fmaf(ud, w4.w, aw);
            }
            *(float4*)&uh[(n << 4) + (fg << 2)] = make_float4(ax, ay, az, aw);
        }
    }
    __syncthreads();

    for (int it = 0; it < 3; ++it) {
        float m = -1e30f;
        for (int i = t; i < 1152; i += 256) m = fmaxf(m, bl[i]);
        #pragma unroll
        for (int o = 32; o > 0; o >>= 1) m = fmaxf(m, __shfl_xor(m, o));
        if (lane == 0) rtmp[wid] = m;
        __syncthreads();
        m = fmaxf(fmaxf(rtmp[0], rtmp[1]), fmaxf(rtmp[2], rtmp[3]));
        float sum = 0.f;
        for (int i = t; i < 1152; i += 256) {
            float e = expf(bl[i] - m);
            cl[i] = e;
            sum += e;
        }
        #pragma unroll
        for (int o = 32; o > 0; o >>= 1) sum += __shfl_xor(sum, o);
        if (lane == 0) rtmp[4 + wid] = sum;
        __syncthreads();
        float inv = 1.f / (rtmp[4] + rtmp[5] + rtmp[6] + rtmp[7]);

        const int f = t & 15, g = t >> 4;
        float sacc = 0.f;
        for (int n = g; n < 1152; n += 16)
            sacc = fmaf(cl[n], uh[(n << 4) + f], sacc);
        red[(g << 4) + f] = sacc;
        __syncthreads();
        if (t < 16) {
            float sv = 0.f;
            #pragma unroll
            for (int gg = 0; gg < 16; ++gg) sv += red[(gg << 4) + t];
            sv *= inv;
            float sq = sv * sv;
            #pragma unroll
            for (int o = 8; o > 0; o >>= 1) sq += __shfl_xor(sq, o);
            float scale = (sq / (1.f + sq)) / sqrtf(sq + 1e-8f);
            vv[t] = sv * scale;
        }
        __syncthreads();
        if (it < 2) {
            for (int n = t; n < 1152; n += 256) {
                const float4* up = (const float4*)&uh[n << 4];
                float4 q0 = up[0], q1 = up[1], q2 = up[2], q3 = up[3];
                float dot =
                    q0.x*vv[0]  + q0.y*vv[1]  + q0.z*vv[2]  + q0.w*vv[3] +
                    q1.x*vv[4]  + q1.y*vv[5]  + q1.z*vv[6]  + q1.w*vv[7] +
                    q2.x*vv[8]  + q2.y*vv[9]  + q2.z*vv[10] + q2.w*vv[11] +
                    q3.x*vv[12] + q3.y*vv[13] + q3.z*vv[14] + q3.w*vv[15];
                bl[n] += dot;
            }
            __syncthreads();
        }
    }

    if (t < 16) {
        float v_ = vv[t];
        float s2 = v_ * v_;
        #pragma unroll
        for (int o = 8; o > 0; o >>= 1) s2 += __shfl_xor(s2, o);
        if (t == 0) cp_out[b * 10 + c] = sqrtf(s2 + 1e-8f);
        vbuf[((b * 10 + c) << 4) + t] = v_;
    }
}

// ---------------- decoder ----------------
__global__ __launch_bounds__(256) void decoder_kernel(
    const float* __restrict__ cp, const float* __restrict__ vbuf,
    const float* __restrict__ W1, const float* __restrict__ B1,
    const float* __restrict__ W2, const float* __restrict__ B2,
    const float* __restrict__ W3, const float* __restrict__ B3,
    float* __restrict__ out)
{
    const int b = blockIdx.x, t = threadIdx.x;
    __shared__ float r16[16];
    __shared__ float h1[512];
    __shared__ float h2[1024];

    float best = cp[b * 10];
    int idx = 0;
    #pragma unroll
    for (int cc = 1; cc < 10; ++cc) {
        float p = cp[b * 10 + cc];
        if (p > best) { best = p; idx = cc; }
    }
    if (t < 16) r16[t] = vbuf[(b * 10 + idx) * 16 + t];
    __syncthreads();

    {
        float a0 = B1[t], a1 = B1[t + 256];
        const float* w = W1 + (size_t)idx * 16 * 512 + t;
        #pragma unroll
        for (int k = 0; k < 16; ++k) {
            float rv = r16[k];
            a0 = fmaf(rv, w[k * 512], a0);
            a1 = fmaf(rv, w[k * 512 + 256], a1);
        }
        h1[t] = fmaxf(a0, 0.f);
        h1[t + 256] = fmaxf(a1, 0.f);
    }
    __syncthreads();

    {
        float a0 = B2[t], a1 = B2[t + 256], a2 = B2[t + 512], a3 = B2[t + 768];
        #pragma unroll 4
        for (int k = 0; k < 512; ++k) {
            float hv = h1[k];
            const float* w = W2 + (size_t)k * 1024 + t;
            a0 = fmaf(hv, w[0], a0);
            a1 = fmaf(hv, w[256], a1);
            a2 = fmaf(hv, w[512], a2);
            a3 = fmaf(hv, w[768], a3);
        }
        h2[t] = fmaxf(a0, 0.f);
        h2[t + 256] = fmaxf(a1, 0.f);
        h2[t + 512] = fmaxf(a2, 0.f);
        h2[t + 768] = fmaxf(a3, 0.f);
    }
    __syncthreads();

    {
        float a0 = B3[t], a1 = B3[t + 256], a2 = B3[t + 512];
        #pragma unroll 4
        for (int k = 0; k < 1024; ++k) {
            float hv = h2[k];
            const float* w = W3 + (size_t)k * 784 + t;
            a0 = fmaf(hv, w[0], a0);
            a1 = fmaf(hv, w[256], a1);
            a2 = fmaf(hv, w[512], a2);
        }
        size_t ob = (size_t)b * 784;
        out[ob + t]       = 1.f / (1.f + expf(-a0));
        out[ob + t + 256] = 1.f / (1.f + expf(-a1));
        out[ob + t + 512] = 1.f / (1.f + expf(-a2));
        if (t < 16) {
            float a3 = B3[t + 768];
            for (int k = 0; k < 1024; ++k)
                a3 = fmaf(h2[k], W3[(size_t)k * 784 + t + 768], a3);
            out[ob + t + 768] = 1.f / (1.f + expf(-a3));
        }
    }
}

extern "C" void kernel_launch(void* const* d_in, const int* in_sizes, int n_in,
                              void* d_out, int out_size, void* d_ws, size_t ws_size,
                              hipStream_t stream) {
    const float* x   = (const float*)d_in[0];
    const float* w1  = (const float*)d_in[1];
    const float* b1  = (const float*)d_in[2];
    const float* w2  = (const float*)d_in[3];
    const float* b2  = (const float*)d_in[4];
    const float* W   = (const float*)d_in[5];
    const float* dw1 = (const float*)d_in[6];
    const float* db1 = (const float*)d_in[7];
    const float* dw2 = (const float*)d_in[8];
    const float* db2 = (const float*)d_in[9];
    const float* dw3 = (const float*)d_in[10];
    const float* db3 = (const float*)d_in[11];

    float* ws   = (float*)d_ws;
    float* outp = (float*)d_out;

    const size_t avail = ws_size / 4;   // f32 slots
    int ks = 0;
    if      (avail >= 31522816ull + 4*2359296ull + 40960ull) ks = 4;
    else if (avail >= 31522816ull + 2*2359296ull + 40960ull) ks = 2;
    else if (avail >= 31522816ull + 1*2359296ull + 40960ull) ks = 1;

    if (ks > 0) {
        bf16* Ah = (bf16*)ws;                          // 26214400 bf16
        bf16* Al = (bf16*)(ws + 13107200);
        bf16* Wh = (bf16*)(ws + 26214400);             // 5308416 bf16
        bf16* Wl = (bf16*)(ws + 28868608);
        float* partial = ws + 31522816;                // ks*2359296 f32
        float* vbuf = ws + 31522816 + (size_t)ks * 2359296;
        float* u = ws;                                 // overlays Ah after conv2

        conv1_kernel<<<dim3(16, 256), 256, 0, stream>>>(x, w1, b1, Ah, Al, nullptr, 0);
        wprep_kernel<<<256, 256, 0, stream>>>(w2, Wh, Wl);
        conv2_mfma<<<72 * 2 * ks, 256, 0, stream>>>(Ah, Al, Wh, Wl, partial, ks, 648 / ks);
        reduce_kernel<<<256, 256, 0, stream>>>(partial, b2, u, ks);
        routing_kernel<<<dim3(256, 10), 256, 0, stream>>>(u, W, outp, vbuf);
        decoder_kernel<<<256, 256, 0, stream>>>(outp, vbuf, dw1, db1, dw2, db2, dw3, db3, outp + 2560);
    } else {
        // fallback: round-0 fp32 path (needs ~114.5 MB)
        float* c1   = ws;
        float* c2   = c1 + 26214400;
        float* vbuf = c2 + 2359296;
        conv1_kernel<<<dim3(16, 256), 256, 0, stream>>>(x, w1, b1, nullptr, nullptr, c1, 1);
        conv2_kernel<<<dim3(4, 64), 384, 0, stream>>>(c1, w2, b2, c2);
        squash_kernel<<<1152, 256, 0, stream>>>(c2);
        routing_kernel<<<dim3(256, 10), 256, 0, stream>>>(c2, W, outp, vbuf);
        decoder_kernel<<<256, 256, 0, stream>>>(outp, vbuf, dw1, db1, dw2, db2, dw3, db3, outp + 2560);
    }
}

// Round 4
// 782.438 us; speedup vs baseline: 3.1594x; 1.1204x over previous
//
#include <hip/hip_runtime.h>
#include <hip/hip_bf16.h>
#include <math.h>

typedef __bf16 bf16;
typedef bf16 bf16x8 __attribute__((ext_vector_type(8)));
typedef float f32x16 __attribute__((ext_vector_type(16)));

// ws layout (f32 slot offsets), fast path:
//   Ah  bf16[26214400] @ 0           (13107200 f32 slots)
//   Al  bf16[26214400] @ 13107200
//   Wh  bf16[5308416]  @ 26214400    (dead after conv2; h1/h2 overlay here)
//   Wl  bf16[5308416]  @ 28868608
//   partial f32 ks*2359296 @ 31522816
//   vbuf f32 40960 @ 31522816 + ks*2359296
//   u   f32[2359296]  @ 0 (overlays Ah after conv2 is done)
//   h1  f32[131072]   @ 26214400 (overlays Wh)
//   h2  f32[262144]   @ 26345472

// ---------------- conv1: x[256,1,28,28] -> bf16 hi/lo channels-last [b][400][256]
__global__ __launch_bounds__(256) void conv1_kernel(
    const float* __restrict__ x, const float* __restrict__ w,
    const float* __restrict__ bias, bf16* __restrict__ outh,
    bf16* __restrict__ outl, float* __restrict__ outf, int mode)
{
    const int b = blockIdx.y;
    const int cg = blockIdx.x;       // 16 groups of 16 channels
    const int t = threadIdx.x;

    __shared__ float xs[784];
    __shared__ float wt[81 * 16];
    __shared__ float bs[16];

    for (int i = t; i < 784; i += 256) xs[i] = x[b * 784 + i];
    for (int i = t; i < 1296; i += 256) {
        int k = i >> 4, cc = i & 15;
        wt[i] = w[(cg * 16 + cc) * 81 + k];
    }
    if (t < 16) bs[t] = bias[cg * 16 + t];
    __syncthreads();

    if (t >= 200) return;
    const int pos = t * 2;
    const int oy = pos / 20, ox = pos % 20;
    float4 A0[4], A1[4];
    #pragma unroll
    for (int g = 0; g < 4; ++g) { A0[g] = make_float4(0,0,0,0); A1[g] = make_float4(0,0,0,0); }

    for (int ky = 0; ky < 9; ++ky) {
        const float* xr = &xs[(oy + ky) * 28 + ox];
        #pragma unroll
        for (int kx = 0; kx < 9; ++kx) {
            float x0 = xr[kx], x1 = xr[kx + 1];
            const float4* wp = (const float4*)&wt[(ky * 9 + kx) << 4];
            #pragma unroll
            for (int g = 0; g < 4; ++g) {
                float4 wv = wp[g];
                A0[g].x = fmaf(x0, wv.x, A0[g].x); A0[g].y = fmaf(x0, wv.y, A0[g].y);
                A0[g].z = fmaf(x0, wv.z, A0[g].z); A0[g].w = fmaf(x0, wv.w, A0[g].w);
                A1[g].x = fmaf(x1, wv.x, A1[g].x); A1[g].y = fmaf(x1, wv.y, A1[g].y);
                A1[g].z = fmaf(x1, wv.z, A1[g].z); A1[g].w = fmaf(x1, wv.w, A1[g].w);
            }
        }
    }

    float va[16], vb[16];
    #pragma unroll
    for (int g = 0; g < 4; ++g) {
        va[g*4+0] = fmaxf(A0[g].x + bs[g*4+0], 0.f);
        va[g*4+1] = fmaxf(A0[g].y + bs[g*4+1], 0.f);
        va[g*4+2] = fmaxf(A0[g].z + bs[g*4+2], 0.f);
        va[g*4+3] = fmaxf(A0[g].w + bs[g*4+3], 0.f);
        vb[g*4+0] = fmaxf(A1[g].x + bs[g*4+0], 0.f);
        vb[g*4+1] = fmaxf(A1[g].y + bs[g*4+1], 0.f);
        vb[g*4+2] = fmaxf(A1[g].z + bs[g*4+2], 0.f);
        vb[g*4+3] = fmaxf(A1[g].w + bs[g*4+3], 0.f);
    }

    if (mode == 0) {
        size_t base0 = ((size_t)b * 400 + pos) * 256 + cg * 16;
        bf16x8 H, L;
        #pragma unroll
        for (int q = 0; q < 8; ++q) { bf16 hh = (bf16)va[q]; H[q] = hh; L[q] = (bf16)(va[q] - (float)hh); }
        *(bf16x8*)(outh + base0) = H; *(bf16x8*)(outl + base0) = L;
        #pragma unroll
        for (int q = 0; q < 8; ++q) { bf16 hh = (bf16)va[8+q]; H[q] = hh; L[q] = (bf16)(va[8+q] - (float)hh); }
        *(bf16x8*)(outh + base0 + 8) = H; *(bf16x8*)(outl + base0 + 8) = L;
        size_t base1 = base0 + 256;
        #pragma unroll
        for (int q = 0; q < 8; ++q) { bf16 hh = (bf16)vb[q]; H[q] = hh; L[q] = (bf16)(vb[q] - (float)hh); }
        *(bf16x8*)(outh + base1) = H; *(bf16x8*)(outl + base1) = L;
        #pragma unroll
        for (int q = 0; q < 8; ++q) { bf16 hh = (bf16)vb[8+q]; H[q] = hh; L[q] = (bf16)(vb[8+q] - (float)hh); }
        *(bf16x8*)(outh + base1 + 8) = H; *(bf16x8*)(outl + base1 + 8) = L;
    } else {
        #pragma unroll
        for (int q = 0; q < 16; ++q) {
            size_t base = (size_t)(b * 256 + cg * 16 + q) * 400 + pos;
            outf[base] = va[q]; outf[base + 1] = vb[q];
        }
    }
}

// ---------------- weight prep: w[co][ci][81] f32 -> Wh/Wl bf16 [tap][co][ci] ----------------
__global__ __launch_bounds__(256) void wprep_kernel(
    const float* __restrict__ w, bf16* __restrict__ Wh, bf16* __restrict__ Wl)
{
    const int co = blockIdx.x, t = threadIdx.x;
    __shared__ float wl[20736];
    for (int i = t; i < 20736; i += 256) wl[i] = w[(size_t)co * 20736 + i];
    __syncthreads();
    for (int tap = 0; tap < 81; ++tap) {
        float f = wl[t * 81 + tap];
        bf16 h = (bf16)f;
        size_t o = ((size_t)tap * 256 + co) * 256 + t;
        Wh[o] = h;
        Wl[o] = (bf16)(f - (float)h);
    }
}

// ---------------- conv2 via split-bf16 MFMA, split-K, depth-2 prefetch, dbuf LDS ----------------
struct C2Regs { bf16x8 ah0, ah1, al0, al1, bh0, bh1, bl0, bl1; };

#define C2_LOADSET(R, gstep) do { \
    const int tap_ = (gstep) >> 3; \
    const int cic_ = ((gstep) & 7) << 5; \
    const int ky_ = tap_ / 9, kx_ = tap_ - ky_ * 9; \
    const int aoff_ = (ky_ * 20 + kx_) * 256 + cic_; \
    const int boff_ = tap_ * 65536 + cic_; \
    R.ah0 = *(const bf16x8*)(Ah + pa0 + aoff_); \
    R.ah1 = *(const bf16x8*)(Ah + pa1 + aoff_); \
    R.al0 = *(const bf16x8*)(Al + pa0 + aoff_); \
    R.al1 = *(const bf16x8*)(Al + pa1 + aoff_); \
    R.bh0 = *(const bf16x8*)(Bh + pb0 + boff_); \
    R.bh1 = *(const bf16x8*)(Bh + pb1 + boff_); \
    R.bl0 = *(const bf16x8*)(Bl + pb0 + boff_); \
    R.bl1 = *(const bf16x8*)(Bl + pb1 + boff_); \
} while (0)

#define C2_STORESET(BB, R) do { \
    *(bf16x8*)&sAh[BB][d0] = R.ah0; *(bf16x8*)&sAh[BB][d1] = R.ah1; \
    *(bf16x8*)&sAl[BB][d0] = R.al0; *(bf16x8*)&sAl[BB][d1] = R.al1; \
    *(bf16x8*)&sBh[BB][d0] = R.bh0; *(bf16x8*)&sBh[BB][d1] = R.bh1; \
    *(bf16x8*)&sBl[BB][d0] = R.bl0; *(bf16x8*)&sBl[BB][d1] = R.bl1; \
} while (0)

// NOTE: second fragment of the wave's 64x64 tile is +32 rows = +32*40 = +1280 elems
#define C2_COMPUTE(BB) do { \
    _Pragma("unroll") \
    for (int h = 0; h < 2; ++h) { \
        const int o = h * 16; \
        bf16x8 a0h = *(const bf16x8*)&sAh[BB][la + o]; \
        bf16x8 a0l = *(const bf16x8*)&sAl[BB][la + o]; \
        bf16x8 a1h = *(const bf16x8*)&sAh[BB][la + 1280 + o]; \
        bf16x8 a1l = *(const bf16x8*)&sAl[BB][la + 1280 + o]; \
        bf16x8 b0h = *(const bf16x8*)&sBh[BB][lb + o]; \
        bf16x8 b0l = *(const bf16x8*)&sBl[BB][lb + o]; \
        bf16x8 b1h = *(const bf16x8*)&sBh[BB][lb + 1280 + o]; \
        bf16x8 b1l = *(const bf16x8*)&sBl[BB][lb + 1280 + o]; \
        acc00 = __builtin_amdgcn_mfma_f32_32x32x16_bf16(a0h, b0h, acc00, 0, 0, 0); \
        acc00 = __builtin_amdgcn_mfma_f32_32x32x16_bf16(a0h, b0l, acc00, 0, 0, 0); \
        acc00 = __builtin_amdgcn_mfma_f32_32x32x16_bf16(a0l, b0h, acc00, 0, 0, 0); \
        acc01 = __builtin_amdgcn_mfma_f32_32x32x16_bf16(a0h, b1h, acc01, 0, 0, 0); \
        acc01 = __builtin_amdgcn_mfma_f32_32x32x16_bf16(a0h, b1l, acc01, 0, 0, 0); \
        acc01 = __builtin_amdgcn_mfma_f32_32x32x16_bf16(a0l, b1h, acc01, 0, 0, 0); \
        acc10 = __builtin_amdgcn_mfma_f32_32x32x16_bf16(a1h, b0h, acc10, 0, 0, 0); \
        acc10 = __builtin_amdgcn_mfma_f32_32x32x16_bf16(a1h, b0l, acc10, 0, 0, 0); \
        acc10 = __builtin_amdgcn_mfma_f32_32x32x16_bf16(a1l, b0h, acc10, 0, 0, 0); \
        acc11 = __builtin_amdgcn_mfma_f32_32x32x16_bf16(a1h, b1h, acc11, 0, 0, 0); \
        acc11 = __builtin_amdgcn_mfma_f32_32x32x16_bf16(a1h, b1l, acc11, 0, 0, 0); \
        acc11 = __builtin_amdgcn_mfma_f32_32x32x16_bf16(a1l, b1h, acc11, 0, 0, 0); \
    } \
} while (0)

// one raw barrier per K-step: lgkm drain only (vmem loads stay in flight)
#define C2_BAR() do { \
    asm volatile("s_waitcnt lgkmcnt(0)" ::: "memory"); \
    __builtin_amdgcn_s_barrier(); \
    asm volatile("" ::: "memory"); \
} while (0)

__global__ __launch_bounds__(256, 2) void conv2_mfma(
    const bf16* __restrict__ Ah, const bf16* __restrict__ Al,
    const bf16* __restrict__ Bh, const bf16* __restrict__ Bl,
    float* __restrict__ partial, int nslice, int spk, int xcdmap)
{
    int mblk, combo;
    if (xcdmap) {              // 576 blocks, ncombo=8: give each XCD 9 m-tiles x all combos
        const int idx = blockIdx.x;
        mblk  = 9 * (idx & 7) + (idx >> 3) % 9;
        combo = idx / 72;
    } else {
        const int ncombo = 2 * nslice;
        combo = blockIdx.x % ncombo;
        mblk  = blockIdx.x / ncombo;
    }
    const int coblk = combo & 1;
    const int kslice = combo >> 1;

    const int t = threadIdx.x;
    const int lane = t & 63, wv = t >> 6;
    const int wm = wv >> 1, wn = wv & 1;

    // rows padded to 40 bf16 = 80B; double-buffered
    __shared__ bf16 sAh[2][128 * 40], sAl[2][128 * 40];
    __shared__ bf16 sBh[2][128 * 40], sBl[2][128 * 40];

    const int slot = t & 3;
    const int r0 = t >> 2;                  // 0..63
    const int m0 = mblk * 128 + r0;
    const int m1 = m0 + 64;
    const int b0 = m0 / 36, s0 = m0 % 36;
    const int b1 = m1 / 36, s1 = m1 % 36;
    const int pa0 = b0 * 102400 + ((s0 / 6) * 40 + (s0 % 6) * 2) * 256 + slot * 8;
    const int pa1 = b1 * 102400 + ((s1 / 6) * 40 + (s1 % 6) * 2) * 256 + slot * 8;
    const int pb0 = (coblk * 128 + r0) * 256 + slot * 8;
    const int pb1 = pb0 + 64 * 256;

    const int d0 = r0 * 40 + slot * 8;
    const int d1 = d0 + 64 * 40;

    const int la = (wm * 64 + (lane & 31)) * 40 + (lane >> 5) * 8;
    const int lb = (wn * 64 + (lane & 31)) * 40 + (lane >> 5) * 8;

    f32x16 acc00 = {}, acc01 = {}, acc10 = {}, acc11 = {};

    const int g0 = kslice * spk;
    C2Regs r0s, r1s;
    C2_LOADSET(r0s, g0);
    C2_LOADSET(r1s, g0 + 1);

    for (int s = 0; s < spk; s += 2) {      // spk always even (648/ks, ks in {1,2,4})
        C2_STORESET(0, r0s);
        C2_BAR();
        if (s + 2 < spk) C2_LOADSET(r0s, g0 + s + 2);
        C2_COMPUTE(0);

        C2_STORESET(1, r1s);
        C2_BAR();
        if (s + 3 < spk) C2_LOADSET(r1s, g0 + s + 3);
        C2_COMPUTE(1);
    }

    float* pp = partial + (size_t)kslice * 2359296;
    const int colb = coblk * 128 + wn * 64 + (lane & 31);
    const int rowb = mblk * 128 + wm * 64 + 4 * (lane >> 5);
    #pragma unroll
    for (int a = 0; a < 2; ++a) {
        #pragma unroll
        for (int nb = 0; nb < 2; ++nb) {
            const f32x16 v = (a == 0) ? (nb == 0 ? acc00 : acc01) : (nb == 0 ? acc10 : acc11);
            const int col = colb + nb * 32;
            const int rb = rowb + a * 32;
            #pragma unroll
            for (int r = 0; r < 16; ++r) {
                int row = rb + (r & 3) + 8 * (r >> 2);
                pp[(size_t)row * 256 + col] = v[r];
            }
        }
    }
}

// ---------------- reduce split-K + bias + relu + squash -> u[b][9216] ----------------
__global__ __launch_bounds__(256) void reduce_kernel(
    const float* __restrict__ partial, const float* __restrict__ bias,
    float* __restrict__ u, int ks)
{
    const int b = blockIdx.x, t = threadIdx.x;
    __shared__ float ld[36 * 257];
    for (int s = 0; s < 36; ++s) {
        size_t idx = ((size_t)b * 36 + s) * 256 + t;
        float a = bias[t];
        for (int k = 0; k < ks; ++k) a += partial[(size_t)k * 2359296 + idx];
        ld[s * 257 + t] = fmaxf(a, 0.f);
    }
    __syncthreads();
    for (int n = t; n < 1152; n += 256) {
        const int f0 = n * 8;
        float vals[8]; float sq = 0.f;
        int co = f0 / 36;
        int s = f0 - co * 36;
        #pragma unroll
        for (int d = 0; d < 8; ++d) {
            float v = ld[s * 257 + co];
            vals[d] = v; sq += v * v;
            if (++s == 36) { s = 0; ++co; }
        }
        float scale = (sq / (1.f + sq)) / sqrtf(sq + 1e-8f);
        #pragma unroll
        for (int d = 0; d < 8; ++d) u[(size_t)b * 9216 + f0 + d] = vals[d] * scale;
    }
}

// ---------------- OLD fallback conv2 (fp32) + squash ----------------
#define C2_CHUNK 2
__global__ __launch_bounds__(384) void conv2_kernel(
    const float* __restrict__ in, const float* __restrict__ w,
    const float* __restrict__ bias, float* __restrict__ out)
{
    const int bg = blockIdx.y;
    const int ct = blockIdx.x;
    const int t = threadIdx.x;

    __shared__ float wl[C2_CHUNK][81][64];
    __shared__ float il[C2_CHUNK][4][20][24];

    const int cg = t & 15;
    const int slot = t >> 4;
    const int bb = slot / 6;
    const int oy = slot % 6;

    float4 acc[6];
    #pragma unroll
    for (int i = 0; i < 6; ++i) acc[i] = make_float4(0,0,0,0);

    for (int cc0 = 0; cc0 < 256; cc0 += C2_CHUNK) {
        for (int idx = t; idx < C2_CHUNK * 5184; idx += 384) {
            int ci = idx / 5184;
            int r = idx - ci * 5184;
            int kk = r >> 6;
            int co = r & 63;
            wl[ci][kk][co] = w[(size_t)(ct * 64 + co) * 20736 + (cc0 + ci) * 81 + kk];
        }
        for (int idx = t; idx < C2_CHUNK * 1600; idx += 384) {
            int ci = idx / 1600;
            int r = idx - ci * 1600;
            int bb2 = r / 400;
            int p = r - bb2 * 400;
            int y = p / 20;
            int xx = p - y * 20;
            il[ci][bb2][y][(xx & 1) * 12 + (xx >> 1)] =
                in[(size_t)((bg * 4 + bb2) * 256 + cc0 + ci) * 400 + p];
        }
        __syncthreads();

        #pragma unroll
        for (int ci = 0; ci < C2_CHUNK; ++ci) {
            for (int ky = 0; ky < 9; ++ky) {
                const int y = oy * 2 + ky;
                const float4* rowp = (const float4*)&il[ci][bb][y][0];
                float a[24];
                #pragma unroll
                for (int q = 0; q < 6; ++q) *(((float4*)a) + q) = rowp[q];
                #pragma unroll
                for (int kx = 0; kx < 9; ++kx) {
                    const int k = ky * 9 + kx;
                    float4 wv = *(const float4*)&wl[ci][k][cg * 4];
                    const int base = (kx & 1) ? (12 + (kx >> 1)) : (kx >> 1);
                    #pragma unroll
                    for (int ox = 0; ox < 6; ++ox) {
                        float av = a[base + ox];
                        acc[ox].x = fmaf(av, wv.x, acc[ox].x);
                        acc[ox].y = fmaf(av, wv.y, acc[ox].y);
                        acc[ox].z = fmaf(av, wv.z, acc[ox].z);
                        acc[ox].w = fmaf(av, wv.w, acc[ox].w);
                    }
                }
            }
        }
        __syncthreads();
    }

    const int b = bg * 4 + bb;
    const int c0 = ct * 64 + cg * 4;
    float4 bv = *(const float4*)&bias[c0];
    #pragma unroll
    for (int ox = 0; ox < 6; ++ox) {
        int sdx = oy * 6 + ox;
        size_t ob = (size_t)b * 9216 + sdx;
        out[ob + (size_t)(c0 + 0) * 36] = fmaxf(acc[ox].x + bv.x, 0.f);
        out[ob + (size_t)(c0 + 1) * 36] = fmaxf(acc[ox].y + bv.y, 0.f);
        out[ob + (size_t)(c0 + 2) * 36] = fmaxf(acc[ox].z + bv.z, 0.f);
        out[ob + (size_t)(c0 + 3) * 36] = fmaxf(acc[ox].w + bv.w, 0.f);
    }
}

__global__ __launch_bounds__(256) void squash_kernel(float* __restrict__ h)
{
    const int cap = blockIdx.x * 256 + threadIdx.x;
    float4* p = (float4*)(h + (size_t)cap * 8);
    float4 v0 = p[0], v1 = p[1];
    float sq = v0.x*v0.x + v0.y*v0.y + v0.z*v0.z + v0.w*v0.w
             + v1.x*v1.x + v1.y*v1.y + v1.z*v1.z + v1.w*v1.w;
    float scale = (sq / (1.f + sq)) / sqrtf(sq + 1e-8f);
    v0.x *= scale; v0.y *= scale; v0.z *= scale; v0.w *= scale;
    v1.x *= scale; v1.y *= scale; v1.z *= scale; v1.w *= scale;
    p[0] = v0; p[1] = v1;
}

// ---------------- fused u_hat + dynamic routing per (b,c); LDS 79.5KB -> 2 blocks/CU -------
__global__ __launch_bounds__(256) void routing_kernel(
    const float* __restrict__ u, const float* __restrict__ W,
    float* __restrict__ cp_out, float* __restrict__ vbuf)
{
    const int b = blockIdx.x;
    const int c = blockIdx.y;
    const int t = threadIdx.x;
    const int lane = t & 63, wid = t >> 6;

    __shared__ float uh[1152 * 16];  // 73.7 KB
    __shared__ float bl[1152];       // 4.6 KB
    __shared__ float red[256];
    __shared__ float rtmp[8];
    __shared__ float vv[16];

    for (int i = t; i < 1152; i += 256) bl[i] = 0.f;

    // u_hat[n][f] = sum_d u[b][n][d] * W[c][n][d][f]   (u read straight from L2)
    {
        const int fg = t & 3, ng = t >> 2;
        const float* Wc = W + (size_t)c * 147456;
        const float* ub = u + (size_t)b * 9216;
        for (int j = 0; j < 18; ++j) {
            int n = ng + (j << 6);
            const float* wn = Wc + n * 128 + fg * 4;
            float4 u0 = *(const float4*)(ub + n * 8);
            float4 u1 = *(const float4*)(ub + n * 8 + 4);
            float ud[8] = {u0.x, u0.y, u0.z, u0.w, u1.x, u1.y, u1.z, u1.w};
            float ax = 0.f, ay = 0.f, az = 0.f, aw = 0.f;
            #pragma unroll
            for (int d = 0; d < 8; ++d) {
                float4 w4 = *(const float4*)(wn + (d << 4));
                ax = fmaf(ud[d], w4.x, ax);
                ay = fmaf(ud[d], w4.y, ay);
                az = fmaf(ud[d], w4.z, az);
                aw = fmaf(ud[d], w4.w, aw);
            }
            *(float4*)&uh[(n << 4) + (fg << 2)] = make_float4(ax, ay, az, aw);
        }
    }
    __syncthreads();

    for (int it = 0; it < 3; ++it) {
        // softmax over n: max
        float m = -1e30f;
        for (int i = t; i < 1152; i += 256) m = fmaxf(m, bl[i]);
        #pragma unroll
        for (int o = 32; o > 0; o >>= 1) m = fmaxf(m, __shfl_xor(m, o));
        if (lane == 0) rtmp[wid] = m;
        __syncthreads();
        m = fmaxf(fmaxf(rtmp[0], rtmp[1]), fmaxf(rtmp[2], rtmp[3]));
        // sum of exp (weights recomputed later, bitwise-identical expf)
        float sum = 0.f;
        for (int i = t; i < 1152; i += 256) sum += expf(bl[i] - m);
        #pragma unroll
        for (int o = 32; o > 0; o >>= 1) sum += __shfl_xor(sum, o);
        if (lane == 0) rtmp[4 + wid] = sum;
        __syncthreads();
        float inv = 1.f / (rtmp[4] + rtmp[5] + rtmp[6] + rtmp[7]);

        // s[f] = inv * sum_n exp(bl[n]-m)*uh[n][f]
        const int f = t & 15, g = t >> 4;
        float sacc = 0.f;
        for (int n = g; n < 1152; n += 16)
            sacc = fmaf(expf(bl[n] - m), uh[(n << 4) + f], sacc);
        red[(g << 4) + f] = sacc;
        __syncthreads();
        if (t < 16) {
            float sv = 0.f;
            #pragma unroll
            for (int gg = 0; gg < 16; ++gg) sv += red[(gg << 4) + t];
            sv *= inv;
            float sq = sv * sv;
            #pragma unroll
            for (int o = 8; o > 0; o >>= 1) sq += __shfl_xor(sq, o);
            float scale = (sq / (1.f + sq)) / sqrtf(sq + 1e-8f);
            vv[t] = sv * scale;
        }
        __syncthreads();
        if (it < 2) {
            for (int n = t; n < 1152; n += 256) {
                const float4* up = (const float4*)&uh[n << 4];
                float4 q0 = up[0], q1 = up[1], q2 = up[2], q3 = up[3];
                float dot =
                    q0.x*vv[0]  + q0.y*vv[1]  + q0.z*vv[2]  + q0.w*vv[3] +
                    q1.x*vv[4]  + q1.y*vv[5]  + q1.z*vv[6]  + q1.w*vv[7] +
                    q2.x*vv[8]  + q2.y*vv[9]  + q2.z*vv[10] + q2.w*vv[11] +
                    q3.x*vv[12] + q3.y*vv[13] + q3.z*vv[14] + q3.w*vv[15];
                bl[n] += dot;
            }
            __syncthreads();
        }
    }

    if (t < 16) {
        float v_ = vv[t];
        float s2 = v_ * v_;
        #pragma unroll
        for (int o = 8; o > 0; o >>= 1) s2 += __shfl_xor(s2, o);
        if (t == 0) cp_out[b * 10 + c] = sqrtf(s2 + 1e-8f);
        vbuf[((b * 10 + c) << 4) + t] = v_;
    }
}

// ---------------- decoder: 3 weight-stationary kernels ----------------
__global__ __launch_bounds__(256) void dec1_kernel(
    const float* __restrict__ cp, const float* __restrict__ vbuf,
    const float* __restrict__ W1, const float* __restrict__ B1,
    float* __restrict__ h1)
{
    const int b = blockIdx.x, t = threadIdx.x;
    __shared__ float r16[16];

    float best = cp[b * 10];
    int idx = 0;
    #pragma unroll
    for (int cc = 1; cc < 10; ++cc) {
        float p = cp[b * 10 + cc];
        if (p > best) { best = p; idx = cc; }
    }
    if (t < 16) r16[t] = vbuf[(b * 10 + idx) * 16 + t];
    __syncthreads();

    float a0 = B1[t], a1 = B1[t + 256];
    const float* w = W1 + (size_t)idx * 16 * 512 + t;
    #pragma unroll
    for (int k = 0; k < 16; ++k) {
        float rv = r16[k];
        a0 = fmaf(rv, w[k * 512], a0);
        a1 = fmaf(rv, w[k * 512 + 256], a1);
    }
    h1[(size_t)b * 512 + t] = fmaxf(a0, 0.f);
    h1[(size_t)b * 512 + t + 256] = fmaxf(a1, 0.f);
}

// grid (8, 16): 128 outs x 16 batches per block; thread = (b in 16) x (8-out group)
__global__ __launch_bounds__(256) void dec2_kernel(
    const float* __restrict__ h1, const float* __restrict__ W2,
    const float* __restrict__ B2, float* __restrict__ h2)
{
    const int ot = blockIdx.x, bt = blockIdx.y, t = threadIdx.x;
    const int bb = bt * 16 + (t >> 4);
    const int o = ot * 128 + (t & 15) * 8;

    float acc[8];
    float4 bv0 = *(const float4*)(B2 + o);
    float4 bv1 = *(const float4*)(B2 + o + 4);
    acc[0]=bv0.x; acc[1]=bv0.y; acc[2]=bv0.z; acc[3]=bv0.w;
    acc[4]=bv1.x; acc[5]=bv1.y; acc[6]=bv1.z; acc[7]=bv1.w;

    const float* hr = h1 + (size_t)bb * 512;
    #pragma unroll 4
    for (int k = 0; k < 512; ++k) {
        float hv = hr[k];
        float4 w0 = *(const float4*)(W2 + (size_t)k * 1024 + o);
        float4 w1 = *(const float4*)(W2 + (size_t)k * 1024 + o + 4);
        acc[0] = fmaf(hv, w0.x, acc[0]); acc[1] = fmaf(hv, w0.y, acc[1]);
        acc[2] = fmaf(hv, w0.z, acc[2]); acc[3] = fmaf(hv, w0.w, acc[3]);
        acc[4] = fmaf(hv, w1.x, acc[4]); acc[5] = fmaf(hv, w1.y, acc[5]);
        acc[6] = fmaf(hv, w1.z, acc[6]); acc[7] = fmaf(hv, w1.w, acc[7]);
    }
    float* hw = h2 + (size_t)bb * 1024 + o;
    #pragma unroll
    for (int q = 0; q < 8; ++q) hw[q] = fmaxf(acc[q], 0.f);
}

// grid (13, 16): 64 outs x 16 batches per block; thread = (b in 16) x (4-out group)
__global__ __launch_bounds__(256) void dec3_kernel(
    const float* __restrict__ h2, const float* __restrict__ W3,
    const float* __restrict__ B3, float* __restrict__ out)
{
    const int ot = blockIdx.x, bt = blockIdx.y, t = threadIdx.x;
    const int bb = bt * 16 + (t >> 4);
    const int o = ot * 64 + (t & 15) * 4;
    if (o >= 784) return;

    float4 bv = *(const float4*)(B3 + o);
    float acc[4] = {bv.x, bv.y, bv.z, bv.w};

    const float* hr = h2 + (size_t)bb * 1024;
    #pragma unroll 4
    for (int k = 0; k < 1024; ++k) {
        float hv = hr[k];
        float4 w0 = *(const float4*)(W3 + (size_t)k * 784 + o);
        acc[0] = fmaf(hv, w0.x, acc[0]); acc[1] = fmaf(hv, w0.y, acc[1]);
        acc[2] = fmaf(hv, w0.z, acc[2]); acc[3] = fmaf(hv, w0.w, acc[3]);
    }
    float* ow = out + (size_t)bb * 784 + o;
    #pragma unroll
    for (int q = 0; q < 4; ++q) ow[q] = 1.f / (1.f + expf(-acc[q]));
}

extern "C" void kernel_launch(void* const* d_in, const int* in_sizes, int n_in,
                              void* d_out, int out_size, void* d_ws, size_t ws_size,
                              hipStream_t stream) {
    const float* x   = (const float*)d_in[0];
    const float* w1  = (const float*)d_in[1];
    const float* b1  = (const float*)d_in[2];
    const float* w2  = (const float*)d_in[3];
    const float* b2  = (const float*)d_in[4];
    const float* W   = (const float*)d_in[5];
    const float* dw1 = (const float*)d_in[6];
    const float* db1 = (const float*)d_in[7];
    const float* dw2 = (const float*)d_in[8];
    const float* db2 = (const float*)d_in[9];
    const float* dw3 = (const float*)d_in[10];
    const float* db3 = (const float*)d_in[11];

    float* ws   = (float*)d_ws;
    float* outp = (float*)d_out;

    const size_t avail = ws_size / 4;   // f32 slots
    int ks = 0;
    if      (avail >= 31522816ull + 4*2359296ull + 40960ull) ks = 4;
    else if (avail >= 31522816ull + 2*2359296ull + 40960ull) ks = 2;
    else if (avail >= 31522816ull + 1*2359296ull + 40960ull) ks = 1;

    if (ks > 0) {
        bf16* Ah = (bf16*)ws;
        bf16* Al = (bf16*)(ws + 13107200);
        bf16* Wh = (bf16*)(ws + 26214400);
        bf16* Wl = (bf16*)(ws + 28868608);
        float* partial = ws + 31522816;
        float* vbuf = ws + 31522816 + (size_t)ks * 2359296;
        float* u  = ws;                       // overlays Ah after conv2
        float* h1 = ws + 26214400;            // overlays Wh after conv2
        float* h2 = ws + 26345472;

        conv1_kernel<<<dim3(16, 256), 256, 0, stream>>>(x, w1, b1, Ah, Al, nullptr, 0);
        wprep_kernel<<<256, 256, 0, stream>>>(w2, Wh, Wl);
        conv2_mfma<<<72 * 2 * ks, 256, 0, stream>>>(Ah, Al, Wh, Wl, partial, ks, 648 / ks,
                                                    ks == 4 ? 1 : 0);
        reduce_kernel<<<256, 256, 0, stream>>>(partial, b2, u, ks);
        routing_kernel<<<dim3(256, 10), 256, 0, stream>>>(u, W, outp, vbuf);
        dec1_kernel<<<256, 256, 0, stream>>>(outp, vbuf, dw1, db1, h1);
        dec2_kernel<<<dim3(8, 16), 256, 0, stream>>>(h1, dw2, db2, h2);
        dec3_kernel<<<dim3(13, 16), 256, 0, stream>>>(h2, dw3, db3, outp + 2560);
    } else {
        // fallback: fp32 path
        float* c1   = ws;
        float* c2   = c1 + 26214400;
        float* vbuf = c2 + 2359296;
        float* h1   = vbuf + 40960;
        float* h2   = h1 + 131072;
        conv1_kernel<<<dim3(16, 256), 256, 0, stream>>>(x, w1, b1, nullptr, nullptr, c1, 1);
        conv2_kernel<<<dim3(4, 64), 384, 0, stream>>>(c1, w2, b2, c2);
        squash_kernel<<<1152, 256, 0, stream>>>(c2);
        routing_kernel<<<dim3(256, 10), 256, 0, stream>>>(c2, W, outp, vbuf);
        dec1_kernel<<<256, 256, 0, stream>>>(outp, vbuf, dw1, db1, h1);
        dec2_kernel<<<dim3(8, 16), 256, 0, stream>>>(h1, dw2, db2, h2);
        dec3_kernel<<<dim3(13, 16), 256, 0, stream>>>(h2, dw3, db3, outp + 2560);
    }
}

// Round 5
// 600.665 us; speedup vs baseline: 4.1154x; 1.3026x over previous
//
#include <hip/hip_runtime.h>
#include <hip/hip_bf16.h>
#include <math.h>

typedef _Float16 f16;
typedef f16 f16x8 __attribute__((ext_vector_type(8)));
typedef float f32x16 __attribute__((ext_vector_type(16)));

// ws layout (f32 slot offsets), fast path:
//   Af16 f16[26214400] @ 0            (13107200 f32 slots)  [b][400pos][256ci]
//   Wf16 f16[5308416]  @ 13107200     (2654208 slots)       [81tap][256co][256ci]
//   partial f32 ks*2359296 @ 15761408
//   vbuf f32 40960 @ 15761408 + ks*2359296
//   u  f32[2359296] @ 0        (overlays Af16 after conv2)
//   h1 f32[131072]  @ 13107200 (overlays Wf16 after conv2)
//   h2 f32[262144]  @ 13238272

// ---------------- conv1: x[256,1,28,28] -> f16 channels-last [b][400][256] (+bias, ReLU)
__global__ __launch_bounds__(256) void conv1_kernel(
    const float* __restrict__ x, const float* __restrict__ w,
    const float* __restrict__ bias, f16* __restrict__ outh,
    float* __restrict__ outf, int mode)
{
    const int b = blockIdx.y;
    const int cg = blockIdx.x;       // 16 groups of 16 channels
    const int t = threadIdx.x;

    __shared__ float xs[784];
    __shared__ float wt[81 * 16];
    __shared__ float bs[16];

    for (int i = t; i < 784; i += 256) xs[i] = x[b * 784 + i];
    for (int i = t; i < 1296; i += 256) {
        int k = i >> 4, cc = i & 15;
        wt[i] = w[(cg * 16 + cc) * 81 + k];
    }
    if (t < 16) bs[t] = bias[cg * 16 + t];
    __syncthreads();

    if (t >= 200) return;
    const int pos = t * 2;
    const int oy = pos / 20, ox = pos % 20;
    float4 A0[4], A1[4];
    #pragma unroll
    for (int g = 0; g < 4; ++g) { A0[g] = make_float4(0,0,0,0); A1[g] = make_float4(0,0,0,0); }

    for (int ky = 0; ky < 9; ++ky) {
        const float* xr = &xs[(oy + ky) * 28 + ox];
        #pragma unroll
        for (int kx = 0; kx < 9; ++kx) {
            float x0 = xr[kx], x1 = xr[kx + 1];
            const float4* wp = (const float4*)&wt[(ky * 9 + kx) << 4];
            #pragma unroll
            for (int g = 0; g < 4; ++g) {
                float4 wv = wp[g];
                A0[g].x = fmaf(x0, wv.x, A0[g].x); A0[g].y = fmaf(x0, wv.y, A0[g].y);
                A0[g].z = fmaf(x0, wv.z, A0[g].z); A0[g].w = fmaf(x0, wv.w, A0[g].w);
                A1[g].x = fmaf(x1, wv.x, A1[g].x); A1[g].y = fmaf(x1, wv.y, A1[g].y);
                A1[g].z = fmaf(x1, wv.z, A1[g].z); A1[g].w = fmaf(x1, wv.w, A1[g].w);
            }
        }
    }

    float va[16], vb[16];
    #pragma unroll
    for (int g = 0; g < 4; ++g) {
        va[g*4+0] = fmaxf(A0[g].x + bs[g*4+0], 0.f);
        va[g*4+1] = fmaxf(A0[g].y + bs[g*4+1], 0.f);
        va[g*4+2] = fmaxf(A0[g].z + bs[g*4+2], 0.f);
        va[g*4+3] = fmaxf(A0[g].w + bs[g*4+3], 0.f);
        vb[g*4+0] = fmaxf(A1[g].x + bs[g*4+0], 0.f);
        vb[g*4+1] = fmaxf(A1[g].y + bs[g*4+1], 0.f);
        vb[g*4+2] = fmaxf(A1[g].z + bs[g*4+2], 0.f);
        vb[g*4+3] = fmaxf(A1[g].w + bs[g*4+3], 0.f);
    }

    if (mode == 0) {
        size_t base0 = ((size_t)b * 400 + pos) * 256 + cg * 16;
        f16x8 H;
        #pragma unroll
        for (int q = 0; q < 8; ++q) H[q] = (f16)va[q];
        *(f16x8*)(outh + base0) = H;
        #pragma unroll
        for (int q = 0; q < 8; ++q) H[q] = (f16)va[8+q];
        *(f16x8*)(outh + base0 + 8) = H;
        size_t base1 = base0 + 256;
        #pragma unroll
        for (int q = 0; q < 8; ++q) H[q] = (f16)vb[q];
        *(f16x8*)(outh + base1) = H;
        #pragma unroll
        for (int q = 0; q < 8; ++q) H[q] = (f16)vb[8+q];
        *(f16x8*)(outh + base1 + 8) = H;
    } else {
        #pragma unroll
        for (int q = 0; q < 16; ++q) {
            size_t base = (size_t)(b * 256 + cg * 16 + q) * 400 + pos;
            outf[base] = va[q]; outf[base + 1] = vb[q];
        }
    }
}

// ---------------- weight prep: w[co][ci][81] f32 -> Wf16 [tap][co][ci] ----------------
__global__ __launch_bounds__(256) void wprep_kernel(
    const float* __restrict__ w, f16* __restrict__ Wf)
{
    const int co = blockIdx.x, t = threadIdx.x;
    __shared__ float wl[20736];
    for (int i = t; i < 20736; i += 256) wl[i] = w[(size_t)co * 20736 + i];
    __syncthreads();
    for (int tap = 0; tap < 81; ++tap) {
        size_t o = ((size_t)tap * 256 + co) * 256 + t;
        Wf[o] = (f16)wl[t * 81 + tap];
    }
}

// ---------------- conv2 fp16 MFMA, split-K, dbuf LDS + XOR swizzle ----------------
// A: [b][400pos][256ci] f16.  B: [81tap][256co][256ci] f16.
// partial[kslice][m=b*36+s][co] f32. block: 128m x 128co, 4 waves (2x2), wave 64x64.
// LDS rows: 32 f16 = 64B, swizzle: byte ^= (row&3)<<4 (slot bits [5:4]).
struct C2R { f16x8 a0, a1, b0, b1; };

#define C2_LOADSET(R, gstep) do { \
    const int tap_ = (gstep) >> 3; \
    const int kc_ = ((gstep) & 7) << 5; \
    const int ky_ = tap_ / 9, kx_ = tap_ - ky_ * 9; \
    const int ao_ = (ky_ * 20 + kx_) * 256 + kc_; \
    const int bo_ = tap_ * 65536 + kc_; \
    R.a0 = *(const f16x8*)(A + paRow + ao_ + sl0 * 8); \
    R.a1 = *(const f16x8*)(A + paRow + ao_ + sl1 * 8); \
    R.b0 = *(const f16x8*)(B + pbRow + bo_ + sl0 * 8); \
    R.b1 = *(const f16x8*)(B + pbRow + bo_ + sl1 * 8); \
} while (0)

#define C2_STORESET(BB, R) do { \
    *(f16x8*)((char*)sA[BB] + wb0) = R.a0; \
    *(f16x8*)((char*)sA[BB] + wb1) = R.a1; \
    *(f16x8*)((char*)sB[BB] + wb0) = R.b0; \
    *(f16x8*)((char*)sB[BB] + wb1) = R.b1; \
} while (0)

#define C2_COMPUTE(BB) do { \
    _Pragma("unroll") \
    for (int h = 0; h < 2; ++h) { \
        f16x8 a0 = *(const f16x8*)((char*)sA[BB] + offA[h]); \
        f16x8 a1 = *(const f16x8*)((char*)sA[BB] + offA[h] + 2048); \
        f16x8 b0 = *(const f16x8*)((char*)sB[BB] + offB[h]); \
        f16x8 b1 = *(const f16x8*)((char*)sB[BB] + offB[h] + 2048); \
        acc00 = __builtin_amdgcn_mfma_f32_32x32x16_f16(a0, b0, acc00, 0, 0, 0); \
        acc01 = __builtin_amdgcn_mfma_f32_32x32x16_f16(a0, b1, acc01, 0, 0, 0); \
        acc10 = __builtin_amdgcn_mfma_f32_32x32x16_f16(a1, b0, acc10, 0, 0, 0); \
        acc11 = __builtin_amdgcn_mfma_f32_32x32x16_f16(a1, b1, acc11, 0, 0, 0); \
    } \
} while (0)

#define C2_BAR() do { \
    asm volatile("s_waitcnt lgkmcnt(0)" ::: "memory"); \
    __builtin_amdgcn_s_barrier(); \
    asm volatile("" ::: "memory"); \
} while (0)

__global__ __launch_bounds__(256, 2) void conv2_f16(
    const f16* __restrict__ A, const f16* __restrict__ B,
    float* __restrict__ partial, int nslice, int spk, int nwg)
{
    // XCD-bijective swizzle (nwg % 8 == 0): each XCD gets contiguous wg chunk
    const int cpx = nwg >> 3;
    const int wg = (blockIdx.x & 7) * cpx + (blockIdx.x >> 3);
    const int ncombo = 2 * nslice;
    const int mblk = wg / ncombo;
    const int combo = wg % ncombo;
    const int coblk = combo & 1;
    const int kslice = combo >> 1;

    const int t = threadIdx.x;
    const int lane = t & 63, wv = t >> 6;
    const int wm = wv >> 1, wn = wv & 1;

    __shared__ f16 sA[2][128 * 32], sB[2][128 * 32];   // 8KB each, 32KB total

    // staging: thread handles row strow, 16B slots sl0,sl1 (32B of the 64B row)
    const int strow = t >> 1;
    const int sl0 = (t & 1) * 2;
    const int sl1 = sl0 + 1;
    const int m0 = mblk * 128 + strow;
    const int b0_ = m0 / 36, s0_ = m0 % 36;
    const int paRow = b0_ * 102400 + ((s0_ / 6) * 40 + (s0_ % 6) * 2) * 256;
    const int pbRow = (coblk * 128 + strow) * 256;

    // LDS write byte offsets (swizzled)
    const int wb0 = strow * 64 + ((sl0 ^ (strow & 3)) << 4);
    const int wb1 = strow * 64 + ((sl1 ^ (strow & 3)) << 4);

    // LDS read byte offsets per h (swizzled); +2048 = +32 rows (same row&3)
    const int rArow = wm * 64 + (lane & 31);
    const int rBrow = wn * 64 + (lane & 31);
    const int cs = (lane >> 5) << 4;        // 0 or 16
    int offA[2], offB[2];
    #pragma unroll
    for (int h = 0; h < 2; ++h) {
        const int cb = cs + h * 32;         // 0,16,32,48
        offA[h] = rArow * 64 + (cb ^ ((rArow & 3) << 4));
        offB[h] = rBrow * 64 + (cb ^ ((rBrow & 3) << 4));
    }

    f32x16 acc00 = {}, acc01 = {}, acc10 = {}, acc11 = {};

    const int g0 = kslice * spk;
    C2R r0s, r1s;
    C2_LOADSET(r0s, g0);
    C2_LOADSET(r1s, g0 + 1);

    for (int s = 0; s < spk; s += 2) {      // spk even (648/ks, ks in {1,2,4})
        C2_STORESET(0, r0s);
        C2_BAR();
        if (s + 2 < spk) C2_LOADSET(r0s, g0 + s + 2);
        C2_COMPUTE(0);

        C2_STORESET(1, r1s);
        C2_BAR();
        if (s + 3 < spk) C2_LOADSET(r1s, g0 + s + 3);
        C2_COMPUTE(1);
    }

    float* pp = partial + (size_t)kslice * 2359296;
    const int colb = coblk * 128 + wn * 64 + (lane & 31);
    const int rowb = mblk * 128 + wm * 64 + 4 * (lane >> 5);
    #pragma unroll
    for (int a = 0; a < 2; ++a) {
        #pragma unroll
        for (int nb = 0; nb < 2; ++nb) {
            const f32x16 v = (a == 0) ? (nb == 0 ? acc00 : acc01) : (nb == 0 ? acc10 : acc11);
            const int col = colb + nb * 32;
            const int rb = rowb + a * 32;
            #pragma unroll
            for (int r = 0; r < 16; ++r) {
                int row = rb + (r & 3) + 8 * (r >> 2);
                pp[(size_t)row * 256 + col] = v[r];
            }
        }
    }
}

// ---------------- reduce split-K + bias + relu + squash -> u[b][9216] ----------------
__global__ __launch_bounds__(256) void reduce_kernel(
    const float* __restrict__ partial, const float* __restrict__ bias,
    float* __restrict__ u, int ks)
{
    const int b = blockIdx.x, t = threadIdx.x;
    __shared__ float ld[36 * 257];
    for (int s = 0; s < 36; ++s) {
        size_t idx = ((size_t)b * 36 + s) * 256 + t;
        float a = bias[t];
        for (int k = 0; k < ks; ++k) a += partial[(size_t)k * 2359296 + idx];
        ld[s * 257 + t] = fmaxf(a, 0.f);
    }
    __syncthreads();
    for (int n = t; n < 1152; n += 256) {
        const int f0 = n * 8;
        float vals[8]; float sq = 0.f;
        int co = f0 / 36;
        int s = f0 - co * 36;
        #pragma unroll
        for (int d = 0; d < 8; ++d) {
            float v = ld[s * 257 + co];
            vals[d] = v; sq += v * v;
            if (++s == 36) { s = 0; ++co; }
        }
        float scale = (sq / (1.f + sq)) / sqrtf(sq + 1e-8f);
        #pragma unroll
        for (int d = 0; d < 8; ++d) u[(size_t)b * 9216 + f0 + d] = vals[d] * scale;
    }
}

// ---------------- OLD fallback conv2 (fp32) + squash ----------------
#define C2_CHUNK 2
__global__ __launch_bounds__(384) void conv2_kernel(
    const float* __restrict__ in, const float* __restrict__ w,
    const float* __restrict__ bias, float* __restrict__ out)
{
    const int bg = blockIdx.y;
    const int ct = blockIdx.x;
    const int t = threadIdx.x;

    __shared__ float wl[C2_CHUNK][81][64];
    __shared__ float il[C2_CHUNK][4][20][24];

    const int cg = t & 15;
    const int slot = t >> 4;
    const int bb = slot / 6;
    const int oy = slot % 6;

    float4 acc[6];
    #pragma unroll
    for (int i = 0; i < 6; ++i) acc[i] = make_float4(0,0,0,0);

    for (int cc0 = 0; cc0 < 256; cc0 += C2_CHUNK) {
        for (int idx = t; idx < C2_CHUNK * 5184; idx += 384) {
            int ci = idx / 5184;
            int r = idx - ci * 5184;
            int kk = r >> 6;
            int co = r & 63;
            wl[ci][kk][co] = w[(size_t)(ct * 64 + co) * 20736 + (cc0 + ci) * 81 + kk];
        }
        for (int idx = t; idx < C2_CHUNK * 1600; idx += 384) {
            int ci = idx / 1600;
            int r = idx - ci * 1600;
            int bb2 = r / 400;
            int p = r - bb2 * 400;
            int y = p / 20;
            int xx = p - y * 20;
            il[ci][bb2][y][(xx & 1) * 12 + (xx >> 1)] =
                in[(size_t)((bg * 4 + bb2) * 256 + cc0 + ci) * 400 + p];
        }
        __syncthreads();

        #pragma unroll
        for (int ci = 0; ci < C2_CHUNK; ++ci) {
            for (int ky = 0; ky < 9; ++ky) {
                const int y = oy * 2 + ky;
                const float4* rowp = (const float4*)&il[ci][bb][y][0];
                float a[24];
                #pragma unroll
                for (int q = 0; q < 6; ++q) *(((float4*)a) + q) = rowp[q];
                #pragma unroll
                for (int kx = 0; kx < 9; ++kx) {
                    const int k = ky * 9 + kx;
                    float4 wv = *(const float4*)&wl[ci][k][cg * 4];
                    const int base = (kx & 1) ? (12 + (kx >> 1)) : (kx >> 1);
                    #pragma unroll
                    for (int ox = 0; ox < 6; ++ox) {
                        float av = a[base + ox];
                        acc[ox].x = fmaf(av, wv.x, acc[ox].x);
                        acc[ox].y = fmaf(av, wv.y, acc[ox].y);
                        acc[ox].z = fmaf(av, wv.z, acc[ox].z);
                        acc[ox].w = fmaf(av, wv.w, acc[ox].w);
                    }
                }
            }
        }
        __syncthreads();
    }

    const int b = bg * 4 + bb;
    const int c0 = ct * 64 + cg * 4;
    float4 bv = *(const float4*)&bias[c0];
    #pragma unroll
    for (int ox = 0; ox < 6; ++ox) {
        int sdx = oy * 6 + ox;
        size_t ob = (size_t)b * 9216 + sdx;
        out[ob + (size_t)(c0 + 0) * 36] = fmaxf(acc[ox].x + bv.x, 0.f);
        out[ob + (size_t)(c0 + 1) * 36] = fmaxf(acc[ox].y + bv.y, 0.f);
        out[ob + (size_t)(c0 + 2) * 36] = fmaxf(acc[ox].z + bv.z, 0.f);
        out[ob + (size_t)(c0 + 3) * 36] = fmaxf(acc[ox].w + bv.w, 0.f);
    }
}

__global__ __launch_bounds__(256) void squash_kernel(float* __restrict__ h)
{
    const int cap = blockIdx.x * 256 + threadIdx.x;
    float4* p = (float4*)(h + (size_t)cap * 8);
    float4 v0 = p[0], v1 = p[1];
    float sq = v0.x*v0.x + v0.y*v0.y + v0.z*v0.z + v0.w*v0.w
             + v1.x*v1.x + v1.y*v1.y + v1.z*v1.z + v1.w*v1.w;
    float scale = (sq / (1.f + sq)) / sqrtf(sq + 1e-8f);
    v0.x *= scale; v0.y *= scale; v0.z *= scale; v0.w *= scale;
    v1.x *= scale; v1.y *= scale; v1.z *= scale; v1.w *= scale;
    p[0] = v0; p[1] = v1;
}

// ---------------- fused u_hat + dynamic routing; 1D grid with XCD swizzle ----------------
// grid 2560: wg = (idx&7)*320 + idx>>3; c = wg/256 (2 c's per XCD -> W slice L2-resident)
__global__ __launch_bounds__(256) void routing_kernel(
    const float* __restrict__ u, const float* __restrict__ W,
    float* __restrict__ cp_out, float* __restrict__ vbuf)
{
    const int wg = ((blockIdx.x & 7) * 320) + (blockIdx.x >> 3);
    const int c = wg >> 8;
    const int b = wg & 255;
    const int t = threadIdx.x;
    const int lane = t & 63, wid = t >> 6;

    __shared__ float uh[1152 * 16];  // 73.7 KB
    __shared__ float bl[1152];
    __shared__ float red[256];
    __shared__ float rtmp[8];
    __shared__ float vv[16];

    for (int i = t; i < 1152; i += 256) bl[i] = 0.f;

    {
        const int fg = t & 3, ng = t >> 2;
        const float* Wc = W + (size_t)c * 147456;
        const float* ub = u + (size_t)b * 9216;
        for (int j = 0; j < 18; ++j) {
            int n = ng + (j << 6);
            const float* wn = Wc + n * 128 + fg * 4;
            float4 u0 = *(const float4*)(ub + n * 8);
            float4 u1 = *(const float4*)(ub + n * 8 + 4);
            float ud[8] = {u0.x, u0.y, u0.z, u0.w, u1.x, u1.y, u1.z, u1.w};
            float ax = 0.f, ay = 0.f, az = 0.f, aw = 0.f;
            #pragma unroll
            for (int d = 0; d < 8; ++d) {
                float4 w4 = *(const float4*)(wn + (d << 4));
                ax = fmaf(ud[d], w4.x, ax);
                ay = fmaf(ud[d], w4.y, ay);
                az = fmaf(ud[d], w4.z, az);
                aw = fmaf(ud[d], w4.w, aw);
            }
            *(float4*)&uh[(n << 4) + (fg << 2)] = make_float4(ax, ay, az, aw);
        }
    }
    __syncthreads();

    for (int it = 0; it < 3; ++it) {
        float m = -1e30f;
        for (int i = t; i < 1152; i += 256) m = fmaxf(m, bl[i]);
        #pragma unroll
        for (int o = 32; o > 0; o >>= 1) m = fmaxf(m, __shfl_xor(m, o));
        if (lane == 0) rtmp[wid] = m;
        __syncthreads();
        m = fmaxf(fmaxf(rtmp[0], rtmp[1]), fmaxf(rtmp[2], rtmp[3]));
        float sum = 0.f;
        for (int i = t; i < 1152; i += 256) sum += expf(bl[i] - m);
        #pragma unroll
        for (int o = 32; o > 0; o >>= 1) sum += __shfl_xor(sum, o);
        if (lane == 0) rtmp[4 + wid] = sum;
        __syncthreads();
        float inv = 1.f / (rtmp[4] + rtmp[5] + rtmp[6] + rtmp[7]);

        const int f = t & 15, g = t >> 4;
        float sacc = 0.f;
        for (int n = g; n < 1152; n += 16)
            sacc = fmaf(expf(bl[n] - m), uh[(n << 4) + f], sacc);
        red[(g << 4) + f] = sacc;
        __syncthreads();
        if (t < 16) {
            float sv = 0.f;
            #pragma unroll
            for (int gg = 0; gg < 16; ++gg) sv += red[(gg << 4) + t];
            sv *= inv;
            float sq = sv * sv;
            #pragma unroll
            for (int o = 8; o > 0; o >>= 1) sq += __shfl_xor(sq, o);
            float scale = (sq / (1.f + sq)) / sqrtf(sq + 1e-8f);
            vv[t] = sv * scale;
        }
        __syncthreads();
        if (it < 2) {
            for (int n = t; n < 1152; n += 256) {
                const float4* up = (const float4*)&uh[n << 4];
                float4 q0 = up[0], q1 = up[1], q2 = up[2], q3 = up[3];
                float dot =
                    q0.x*vv[0]  + q0.y*vv[1]  + q0.z*vv[2]  + q0.w*vv[3] +
                    q1.x*vv[4]  + q1.y*vv[5]  + q1.z*vv[6]  + q1.w*vv[7] +
                    q2.x*vv[8]  + q2.y*vv[9]  + q2.z*vv[10] + q2.w*vv[11] +
                    q3.x*vv[12] + q3.y*vv[13] + q3.z*vv[14] + q3.w*vv[15];
                bl[n] += dot;
            }
            __syncthreads();
        }
    }

    if (t < 16) {
        float v_ = vv[t];
        float s2 = v_ * v_;
        #pragma unroll
        for (int o = 8; o > 0; o >>= 1) s2 += __shfl_xor(s2, o);
        if (t == 0) cp_out[b * 10 + c] = sqrtf(s2 + 1e-8f);
        vbuf[((b * 10 + c) << 4) + t] = v_;
    }
}

// ---------------- decoder: 3 weight-stationary kernels ----------------
__global__ __launch_bounds__(256) void dec1_kernel(
    const float* __restrict__ cp, const float* __restrict__ vbuf,
    const float* __restrict__ W1, const float* __restrict__ B1,
    float* __restrict__ h1)
{
    const int b = blockIdx.x, t = threadIdx.x;
    __shared__ float r16[16];

    float best = cp[b * 10];
    int idx = 0;
    #pragma unroll
    for (int cc = 1; cc < 10; ++cc) {
        float p = cp[b * 10 + cc];
        if (p > best) { best = p; idx = cc; }
    }
    if (t < 16) r16[t] = vbuf[(b * 10 + idx) * 16 + t];
    __syncthreads();

    float a0 = B1[t], a1 = B1[t + 256];
    const float* w = W1 + (size_t)idx * 16 * 512 + t;
    #pragma unroll
    for (int k = 0; k < 16; ++k) {
        float rv = r16[k];
        a0 = fmaf(rv, w[k * 512], a0);
        a1 = fmaf(rv, w[k * 512 + 256], a1);
    }
    h1[(size_t)b * 512 + t] = fmaxf(a0, 0.f);
    h1[(size_t)b * 512 + t + 256] = fmaxf(a1, 0.f);
}

__global__ __launch_bounds__(256) void dec2_kernel(
    const float* __restrict__ h1, const float* __restrict__ W2,
    const float* __restrict__ B2, float* __restrict__ h2)
{
    const int ot = blockIdx.x, bt = blockIdx.y, t = threadIdx.x;
    const int bb = bt * 16 + (t >> 4);
    const int o = ot * 128 + (t & 15) * 8;

    float acc[8];
    float4 bv0 = *(const float4*)(B2 + o);
    float4 bv1 = *(const float4*)(B2 + o + 4);
    acc[0]=bv0.x; acc[1]=bv0.y; acc[2]=bv0.z; acc[3]=bv0.w;
    acc[4]=bv1.x; acc[5]=bv1.y; acc[6]=bv1.z; acc[7]=bv1.w;

    const float* hr = h1 + (size_t)bb * 512;
    #pragma unroll 4
    for (int k = 0; k < 512; ++k) {
        float hv = hr[k];
        float4 w0 = *(const float4*)(W2 + (size_t)k * 1024 + o);
        float4 w1 = *(const float4*)(W2 + (size_t)k * 1024 + o + 4);
        acc[0] = fmaf(hv, w0.x, acc[0]); acc[1] = fmaf(hv, w0.y, acc[1]);
        acc[2] = fmaf(hv, w0.z, acc[2]); acc[3] = fmaf(hv, w0.w, acc[3]);
        acc[4] = fmaf(hv, w1.x, acc[4]); acc[5] = fmaf(hv, w1.y, acc[5]);
        acc[6] = fmaf(hv, w1.z, acc[6]); acc[7] = fmaf(hv, w1.w, acc[7]);
    }
    float* hw = h2 + (size_t)bb * 1024 + o;
    #pragma unroll
    for (int q = 0; q < 8; ++q) hw[q] = fmaxf(acc[q], 0.f);
}

__global__ __launch_bounds__(256) void dec3_kernel(
    const float* __restrict__ h2, const float* __restrict__ W3,
    const float* __restrict__ B3, float* __restrict__ out)
{
    const int ot = blockIdx.x, bt = blockIdx.y, t = threadIdx.x;
    const int bb = bt * 16 + (t >> 4);
    const int o = ot * 64 + (t & 15) * 4;
    if (o >= 784) return;

    float4 bv = *(const float4*)(B3 + o);
    float acc[4] = {bv.x, bv.y, bv.z, bv.w};

    const float* hr = h2 + (size_t)bb * 1024;
    #pragma unroll 4
    for (int k = 0; k < 1024; ++k) {
        float hv = hr[k];
        float4 w0 = *(const float4*)(W3 + (size_t)k * 784 + o);
        acc[0] = fmaf(hv, w0.x, acc[0]); acc[1] = fmaf(hv, w0.y, acc[1]);
        acc[2] = fmaf(hv, w0.z, acc[2]); acc[3] = fmaf(hv, w0.w, acc[3]);
    }
    float* ow = out + (size_t)bb * 784 + o;
    #pragma unroll
    for (int q = 0; q < 4; ++q) ow[q] = 1.f / (1.f + expf(-acc[q]));
}

extern "C" void kernel_launch(void* const* d_in, const int* in_sizes, int n_in,
                              void* d_out, int out_size, void* d_ws, size_t ws_size,
                              hipStream_t stream) {
    const float* x   = (const float*)d_in[0];
    const float* w1  = (const float*)d_in[1];
    const float* b1  = (const float*)d_in[2];
    const float* w2  = (const float*)d_in[3];
    const float* b2  = (const float*)d_in[4];
    const float* W   = (const float*)d_in[5];
    const float* dw1 = (const float*)d_in[6];
    const float* db1 = (const float*)d_in[7];
    const float* dw2 = (const float*)d_in[8];
    const float* db2 = (const float*)d_in[9];
    const float* dw3 = (const float*)d_in[10];
    const float* db3 = (const float*)d_in[11];

    float* ws   = (float*)d_ws;
    float* outp = (float*)d_out;

    const size_t avail = ws_size / 4;   // f32 slots
    int ks = 0;
    if      (avail >= 15761408ull + 4*2359296ull + 40960ull) ks = 4;
    else if (avail >= 15761408ull + 2*2359296ull + 40960ull) ks = 2;
    else if (avail >= 15761408ull + 1*2359296ull + 40960ull) ks = 1;

    if (ks > 0) {
        f16* Af = (f16*)ws;
        f16* Wf = (f16*)(ws + 13107200);
        float* partial = ws + 15761408;
        float* vbuf = ws + 15761408 + (size_t)ks * 2359296;
        float* u  = ws;                       // overlays Af after conv2
        float* h1 = ws + 13107200;            // overlays Wf after conv2
        float* h2 = ws + 13238272;

        const int nwg = 72 * 2 * ks;
        conv1_kernel<<<dim3(16, 256), 256, 0, stream>>>(x, w1, b1, Af, nullptr, 0);
        wprep_kernel<<<256, 256, 0, stream>>>(w2, Wf);
        conv2_f16<<<nwg, 256, 0, stream>>>(Af, Wf, partial, ks, 648 / ks, nwg);
        reduce_kernel<<<256, 256, 0, stream>>>(partial, b2, u, ks);
        routing_kernel<<<2560, 256, 0, stream>>>(u, W, outp, vbuf);
        dec1_kernel<<<256, 256, 0, stream>>>(outp, vbuf, dw1, db1, h1);
        dec2_kernel<<<dim3(8, 16), 256, 0, stream>>>(h1, dw2, db2, h2);
        dec3_kernel<<<dim3(13, 16), 256, 0, stream>>>(h2, dw3, db3, outp + 2560);
    } else {
        // fallback: fp32 path
        float* c1   = ws;
        float* c2   = c1 + 26214400;
        float* vbuf = c2 + 2359296;
        float* h1   = vbuf + 40960;
        float* h2   = h1 + 131072;
        conv1_kernel<<<dim3(16, 256), 256, 0, stream>>>(x, w1, b1, nullptr, c1, 1);
        conv2_kernel<<<dim3(4, 64), 384, 0, stream>>>(c1, w2, b2, c2);
        squash_kernel<<<1152, 256, 0, stream>>>(c2);
        routing_kernel<<<2560, 256, 0, stream>>>(c2, W, outp, vbuf);
        dec1_kernel<<<256, 256, 0, stream>>>(outp, vbuf, dw1, db1, h1);
        dec2_kernel<<<dim3(8, 16), 256, 0, stream>>>(h1, dw2, db2, h2);
        dec3_kernel<<<dim3(13, 16), 256, 0, stream>>>(h2, dw3, db3, outp + 2560);
    }
}